// Round 1
// baseline (1026.066 us; speedup 1.0000x reference)
//
#include <hip/hip_runtime.h>

#define NN 100000
#define NE 1600000
#define DH 128
#define NG 64
#define NBLK_SCAN 391  // ceil(NN/256)

// ---------------- degree / CSR build ----------------

__global__ void k_count(const int* __restrict__ dst, int* __restrict__ counts) {
  int e = blockIdx.x * blockDim.x + threadIdx.x;
  if (e < NE) atomicAdd(&counts[dst[e]], 1);
}

__global__ void k_dinv(const int* __restrict__ counts, float* __restrict__ dinv) {
  int i = blockIdx.x * blockDim.x + threadIdx.x;
  if (i < NN) dinv[i] = rsqrtf((float)counts[i] + 1.0f);  // +1 = self loop
}

__global__ void k_scan1(const int* __restrict__ counts, int* __restrict__ partial,
                        int* __restrict__ blockSums) {
  __shared__ int tmp[256];
  int i = blockIdx.x * 256 + threadIdx.x;
  tmp[threadIdx.x] = (i < NN) ? counts[i] : 0;
  __syncthreads();
  for (int off = 1; off < 256; off <<= 1) {
    int t = (threadIdx.x >= off) ? tmp[threadIdx.x - off] : 0;
    __syncthreads();
    tmp[threadIdx.x] += t;
    __syncthreads();
  }
  if (i < NN) partial[i] = tmp[threadIdx.x];  // inclusive within block
  if (threadIdx.x == 255) blockSums[blockIdx.x] = tmp[255];
}

__global__ void k_scan2(int* __restrict__ blockSums) {
  __shared__ int tmp[512];
  int t = threadIdx.x;
  tmp[t] = (t < NBLK_SCAN) ? blockSums[t] : 0;
  __syncthreads();
  for (int off = 1; off < 512; off <<= 1) {
    int v = (t >= off) ? tmp[t - off] : 0;
    __syncthreads();
    tmp[t] += v;
    __syncthreads();
  }
  if (t < NBLK_SCAN) blockSums[t] = tmp[t];  // inclusive
}

__global__ void k_scan3(const int* __restrict__ partial, const int* __restrict__ blockSums,
                        const int* __restrict__ counts, int* __restrict__ offsets,
                        int* __restrict__ cursor) {
  int i = blockIdx.x * 256 + threadIdx.x;
  if (i < NN) {
    int b = i >> 8;
    int add = (b > 0) ? blockSums[b - 1] : 0;
    int incl = partial[i] + add;
    offsets[i + 1] = incl;
    cursor[i] = incl - counts[i];  // exclusive start
    if (i == 0) offsets[0] = 0;
  }
}

__global__ void k_fill(const int* __restrict__ src, const int* __restrict__ dst,
                       int* __restrict__ cursor, int* __restrict__ csr_src) {
  int e = blockIdx.x * blockDim.x + threadIdx.x;
  if (e < NE) {
    int p = atomicAdd(&cursor[dst[e]], 1);
    csr_src[p] = src[e];
  }
}

// ---------------- graph boundaries (batch is sorted) ----------------

__global__ void k_starts(const int* __restrict__ batch, int* __restrict__ start) {
  int i = blockIdx.x * blockDim.x + threadIdx.x;
  if (i >= NN) return;
  int b = batch[i];
  int prev = (i == 0) ? -1 : batch[i - 1];
  for (int g = prev + 1; g <= b; ++g) start[g] = i;
  if (i == NN - 1) {
    for (int g = b + 1; g <= NG; ++g) start[g] = NN;
  }
}

// ---------------- GEMM: Out[r][c] = dinv[r] * sum_k A[r][k] * W[k][c] ----------------
// 96 rows x 128 cols per block, 256 threads, 6x8 register tile per thread.
// A tile staged in LDS (stride 129 to break bank aliasing); W read from global (L1/L2-hot, 64KB).

#define GR 96
#define LDA 129

__global__ __launch_bounds__(256) void k_gemm(const float* __restrict__ A,
                                              const float* __restrict__ W,
                                              const float* __restrict__ dinv,
                                              float* __restrict__ Out) {
  __shared__ float Al[GR * LDA];
  int rowBase = blockIdx.x * GR;
  int tid = threadIdx.x;

  // stage A tile: 96 rows x 32 float4
#pragma unroll
  for (int p = 0; p < 12; ++p) {
    int idx = p * 256 + tid;
    int r = idx >> 5;
    int c4 = (idx & 31) * 4;
    int gr = rowBase + r;
    float4 v = {0.f, 0.f, 0.f, 0.f};
    if (gr < NN) v = *(const float4*)(A + (size_t)gr * DH + c4);
    float* dstl = &Al[r * LDA + c4];
    dstl[0] = v.x; dstl[1] = v.y; dstl[2] = v.z; dstl[3] = v.w;
  }
  __syncthreads();

  int tx = tid & 15;   // col group: cols tx*8 .. +7
  int ty = tid >> 4;   // row group: rows ty*6 .. +5

  float acc[6][8];
#pragma unroll
  for (int i = 0; i < 6; ++i)
#pragma unroll
    for (int j = 0; j < 8; ++j) acc[i][j] = 0.f;

  const float* Wp = W + tx * 8;
#pragma unroll 4
  for (int k = 0; k < DH; ++k) {
    float4 w0 = *(const float4*)(Wp + k * DH);
    float4 w1 = *(const float4*)(Wp + k * DH + 4);
    float wv[8] = {w0.x, w0.y, w0.z, w0.w, w1.x, w1.y, w1.z, w1.w};
#pragma unroll
    for (int i = 0; i < 6; ++i) {
      float a = Al[(ty * 6 + i) * LDA + k];
#pragma unroll
      for (int j = 0; j < 8; ++j) acc[i][j] = fmaf(a, wv[j], acc[i][j]);
    }
  }

#pragma unroll
  for (int i = 0; i < 6; ++i) {
    int r = rowBase + ty * 6 + i;
    if (r < NN) {
      float dv = dinv[r];
      float4 o0 = {acc[i][0] * dv, acc[i][1] * dv, acc[i][2] * dv, acc[i][3] * dv};
      float4 o1 = {acc[i][4] * dv, acc[i][5] * dv, acc[i][6] * dv, acc[i][7] * dv};
      *(float4*)(Out + (size_t)r * DH + tx * 8) = o0;
      *(float4*)(Out + (size_t)r * DH + tx * 8 + 4) = o1;
    }
  }
}

// ---------------- aggregation: h[i] = relu(dinv[i]*(sum_{e->i} hs[src] + hs[i]) + b) ----------------
// 32 threads per node (4 dims each as float4); CSR rows; no atomics.

__global__ __launch_bounds__(256) void k_aggregate(const float* __restrict__ hs,
                                                   const int* __restrict__ csr_src,
                                                   const int* __restrict__ offsets,
                                                   const float* __restrict__ dinv,
                                                   const float* __restrict__ bias,
                                                   float* __restrict__ hout) {
  int gid = blockIdx.x * 256 + threadIdx.x;
  int node = gid >> 5;
  int lane4 = (gid & 31) * 4;
  if (node >= NN) return;
  int s = offsets[node];
  int e = offsets[node + 1];

  const float4 self = *(const float4*)(hs + (size_t)node * DH + lane4);
  float ax = self.x, ay = self.y, az = self.z, aw = self.w;

  int p = s;
  for (; p + 1 < e; p += 2) {
    int s0 = csr_src[p];
    int s1 = csr_src[p + 1];
    float4 v0 = *(const float4*)(hs + (size_t)s0 * DH + lane4);
    float4 v1 = *(const float4*)(hs + (size_t)s1 * DH + lane4);
    ax += v0.x + v1.x; ay += v0.y + v1.y; az += v0.z + v1.z; aw += v0.w + v1.w;
  }
  if (p < e) {
    int s0 = csr_src[p];
    float4 v0 = *(const float4*)(hs + (size_t)s0 * DH + lane4);
    ax += v0.x; ay += v0.y; az += v0.z; aw += v0.w;
  }

  float dv = dinv[node];
  float4 b4 = *(const float4*)(bias + lane4);
  float4 r;
  r.x = fmaxf(fmaf(ax, dv, b4.x), 0.f);
  r.y = fmaxf(fmaf(ay, dv, b4.y), 0.f);
  r.z = fmaxf(fmaf(az, dv, b4.z), 0.f);
  r.w = fmaxf(fmaf(aw, dv, b4.w), 0.f);
  *(float4*)(hout + (size_t)node * DH + lane4) = r;
}

// ---------------- pooling: pooled[g][colOff + d] += sum over slice of nodes ----------------

__global__ void k_pool(const float* __restrict__ h, const int* __restrict__ start,
                       float* __restrict__ pooled, int colOff) {
  int g = blockIdx.x;
  int slice = blockIdx.y;
  int t = threadIdx.x;  // 128
  int s0 = start[g], s1 = start[g + 1];
  int len = s1 - s0;
  int per = (len + 7) >> 3;
  int a = s0 + slice * per;
  int b = a + per;
  if (b > s1) b = s1;
  float acc = 0.f;
  for (int i = a; i < b; ++i) acc += h[(size_t)i * DH + t];
  if (per > 0) atomicAdd(&pooled[g * (3 * DH) + colOff + t], acc);
}

// ---------------- head: mean-div, lin1+relu, lin2, log_softmax ----------------

__global__ __launch_bounds__(128) void k_head(const float* __restrict__ pooled,
                                              const int* __restrict__ start,
                                              const float* __restrict__ l1w,
                                              const float* __restrict__ l1b,
                                              const float* __restrict__ l2w,
                                              const float* __restrict__ l2b,
                                              float* __restrict__ out) {
  __shared__ float pr[3 * DH];
  __shared__ float grow[DH];
  __shared__ float lg[16];
  int g = blockIdx.x, t = threadIdx.x;
  float cnt = (float)(start[g + 1] - start[g]);
  float inv = 1.0f / fmaxf(cnt, 1.0f);
  for (int k = t; k < 3 * DH; k += 128) pr[k] = pooled[g * (3 * DH) + k] * inv;
  __syncthreads();
  float acc = l1b[t];
  for (int k = 0; k < 3 * DH; ++k) acc = fmaf(pr[k], l1w[k * DH + t], acc);
  grow[t] = fmaxf(acc, 0.f);
  __syncthreads();
  if (t < 10) {
    float a = l2b[t];
    for (int k = 0; k < DH; ++k) a = fmaf(grow[k], l2w[k * 10 + t], a);
    lg[t] = a;
  }
  __syncthreads();
  if (t < 10) {
    float m = lg[0];
    for (int i = 1; i < 10; ++i) m = fmaxf(m, lg[i]);
    float sum = 0.f;
    for (int i = 0; i < 10; ++i) sum += expf(lg[i] - m);
    out[g * 10 + t] = lg[t] - m - logf(sum);
  }
}

// ---------------- launch ----------------

extern "C" void kernel_launch(void* const* d_in, const int* in_sizes, int n_in,
                              void* d_out, int out_size, void* d_ws, size_t ws_size,
                              hipStream_t stream) {
  const float* x = (const float*)d_in[0];
  const int* ei = (const int*)d_in[1];
  const int* esrc = ei;
  const int* edst = ei + NE;
  const int* batch = (const int*)d_in[2];
  const float* W[3] = {(const float*)d_in[4], (const float*)d_in[6], (const float*)d_in[8]};
  const float* B[3] = {(const float*)d_in[5], (const float*)d_in[7], (const float*)d_in[9]};
  const float* l1w = (const float*)d_in[10];
  const float* l1b = (const float*)d_in[11];
  const float* l2w = (const float*)d_in[12];
  const float* l2b = (const float*)d_in[13];
  float* out = (float*)d_out;

  char* ws = (char*)d_ws;
  size_t off = 0;
  auto alloc = [&](size_t bytes) {
    char* p = ws + off;
    off = (off + bytes + 255) & ~(size_t)255;
    return p;
  };
  int* counts = (int*)alloc((size_t)NN * 4);
  float* dinv = (float*)alloc((size_t)NN * 4);
  int* partial = (int*)alloc((size_t)NN * 4);
  int* blockSums = (int*)alloc(512 * 4);
  int* offsets = (int*)alloc((size_t)(NN + 1) * 4);
  int* cursor = (int*)alloc((size_t)NN * 4);
  int* csr_src = (int*)alloc((size_t)NE * 4);
  int* start = (int*)alloc((NG + 1) * 4);
  float* pooled = (float*)alloc((size_t)NG * 3 * DH * 4);
  float* bufA = (float*)alloc((size_t)NN * DH * 4);  // hs (scaled GEMM out)
  float* bufB = (float*)alloc((size_t)NN * DH * 4);  // h (post-aggregate)

  hipMemsetAsync(counts, 0, (size_t)NN * 4, stream);
  hipMemsetAsync(pooled, 0, (size_t)NG * 3 * DH * 4, stream);

  k_count<<<(NE + 255) / 256, 256, 0, stream>>>(edst, counts);
  k_dinv<<<(NN + 255) / 256, 256, 0, stream>>>(counts, dinv);
  k_scan1<<<NBLK_SCAN, 256, 0, stream>>>(counts, partial, blockSums);
  k_scan2<<<1, 512, 0, stream>>>(blockSums);
  k_scan3<<<(NN + 255) / 256, 256, 0, stream>>>(partial, blockSums, counts, offsets, cursor);
  k_fill<<<(NE + 255) / 256, 256, 0, stream>>>(esrc, edst, cursor, csr_src);
  k_starts<<<(NN + 255) / 256, 256, 0, stream>>>(batch, start);

  const float* gin = x;
  for (int L = 0; L < 3; ++L) {
    k_gemm<<<(NN + GR - 1) / GR, 256, 0, stream>>>(gin, W[L], dinv, bufA);
    k_aggregate<<<(NN * 32) / 256, 256, 0, stream>>>(bufA, csr_src, offsets, dinv, B[L], bufB);
    k_pool<<<dim3(NG, 8), 128, 0, stream>>>(bufB, start, pooled, L * DH);
    gin = bufB;
  }

  k_head<<<NG, 128, 0, stream>>>(pooled, start, l1w, l1b, l2w, l2b, out);
}

// Round 2
// 966.077 us; speedup vs baseline: 1.0621x; 1.0621x over previous
//
#include <hip/hip_runtime.h>

#define NN 100000
#define NE 1600000
#define DH 128
#define NG 64
#define NBLK_SCAN 391  // ceil(NN/256)

// binning parameters for CSR build
#define NBUCK 128          // coarse buckets, bucket = dst >> 10 (max 98 used)
#define EPB 4096           // edges per binning block
#define NBLK_BIN 391       // ceil(NE/EPB)

// ---------------- degree ----------------

__global__ void k_count(const int* __restrict__ dst, int* __restrict__ counts) {
  int e = blockIdx.x * blockDim.x + threadIdx.x;
  if (e < NE) atomicAdd(&counts[dst[e]], 1);
}

__global__ void k_dinv(const int* __restrict__ counts, float* __restrict__ dinv) {
  int i = blockIdx.x * blockDim.x + threadIdx.x;
  if (i < NN) dinv[i] = rsqrtf((float)counts[i] + 1.0f);  // +1 = self loop
}

__global__ void k_scan1(const int* __restrict__ counts, int* __restrict__ partial,
                        int* __restrict__ blockSums) {
  __shared__ int tmp[256];
  int i = blockIdx.x * 256 + threadIdx.x;
  tmp[threadIdx.x] = (i < NN) ? counts[i] : 0;
  __syncthreads();
  for (int off = 1; off < 256; off <<= 1) {
    int t = (threadIdx.x >= off) ? tmp[threadIdx.x - off] : 0;
    __syncthreads();
    tmp[threadIdx.x] += t;
    __syncthreads();
  }
  if (i < NN) partial[i] = tmp[threadIdx.x];  // inclusive within block
  if (threadIdx.x == 255) blockSums[blockIdx.x] = tmp[255];
}

__global__ void k_scan2(int* __restrict__ blockSums) {
  __shared__ int tmp[512];
  int t = threadIdx.x;
  tmp[t] = (t < NBLK_SCAN) ? blockSums[t] : 0;
  __syncthreads();
  for (int off = 1; off < 512; off <<= 1) {
    int v = (t >= off) ? tmp[t - off] : 0;
    __syncthreads();
    tmp[t] += v;
    __syncthreads();
  }
  if (t < NBLK_SCAN) blockSums[t] = tmp[t];  // inclusive
}

__global__ void k_scan3(const int* __restrict__ partial, const int* __restrict__ blockSums,
                        int* __restrict__ offsets) {
  int i = blockIdx.x * 256 + threadIdx.x;
  if (i < NN) {
    int b = i >> 8;
    int add = (b > 0) ? blockSums[b - 1] : 0;
    offsets[i + 1] = partial[i] + add;
    if (i == 0) offsets[0] = 0;
  }
}

// ---------------- CSR build: two-level counting sort (no random scatter) ----

// Pass A: per-(block, bucket) histogram.
__global__ __launch_bounds__(256) void k_binhist(const int* __restrict__ dst,
                                                 int* __restrict__ hist) {
  __shared__ int h[NBUCK];
  if (threadIdx.x < NBUCK) h[threadIdx.x] = 0;
  __syncthreads();
  int base = blockIdx.x * EPB;
#pragma unroll
  for (int i = 0; i < EPB / 256; ++i) {
    int e = base + i * 256 + threadIdx.x;
    if (e < NE) atomicAdd(&h[dst[e] >> 10], 1);
  }
  __syncthreads();
  if (threadIdx.x < NBUCK)
    hist[threadIdx.x * NBLK_BIN + blockIdx.x] = h[threadIdx.x];
}

// Per-bucket exclusive scan across blocks, seeded with bucket's CSR base.
__global__ __launch_bounds__(256) void k_binscan(int* __restrict__ hist,
                                                 const int* __restrict__ offsets) {
  __shared__ int v[NBLK_BIN + 1];
  int b = blockIdx.x;  // bucket
  for (int i = threadIdx.x; i < NBLK_BIN; i += 256)
    v[i] = hist[b * NBLK_BIN + i];
  __syncthreads();
  if (threadIdx.x == 0) {
    int nb = b << 10;
    int running = offsets[nb > NN ? NN : nb];
    for (int i = 0; i < NBLK_BIN; ++i) {
      int t = v[i];
      v[i] = running;
      running += t;
    }
  }
  __syncthreads();
  for (int i = threadIdx.x; i < NBLK_BIN; i += 256)
    hist[b * NBLK_BIN + i] = v[i];
}

// Pass B: place (src,dst) pairs into bucket-major regions; each (block,bucket)
// sub-region is private & contiguous -> full-line writebacks.
__global__ __launch_bounds__(256) void k_binplace(const int* __restrict__ src,
                                                  const int* __restrict__ dst,
                                                  const int* __restrict__ hist,
                                                  int2* __restrict__ pairs) {
  __shared__ int cur[NBUCK];
  if (threadIdx.x < NBUCK)
    cur[threadIdx.x] = hist[threadIdx.x * NBLK_BIN + blockIdx.x];
  __syncthreads();
  int base = blockIdx.x * EPB;
#pragma unroll
  for (int i = 0; i < EPB / 256; ++i) {
    int e = base + i * 256 + threadIdx.x;
    if (e < NE) {
      int d = dst[e];
      int q = atomicAdd(&cur[d >> 10], 1);
      pairs[q] = make_int2(src[e], d);
    }
  }
}

// Final: one block per bucket sorts its pairs into exact CSR slots.
// Writes confined to the bucket's contiguous csr region (single block owner).
__global__ __launch_bounds__(256) void k_place(const int2* __restrict__ pairs,
                                               const int* __restrict__ offsets,
                                               int* __restrict__ csr_src) {
  __shared__ int cur[1024];
  int nodeBase = blockIdx.x << 10;
  for (int i = threadIdx.x; i < 1024; i += 256) {
    int g = nodeBase + i;
    cur[i] = (g < NN) ? offsets[g] : 0;
  }
  __syncthreads();
  int eStart = offsets[nodeBase > NN ? NN : nodeBase];
  int endNode = nodeBase + 1024;
  int eEnd = offsets[endNode > NN ? NN : endNode];
  for (int p = eStart + threadIdx.x; p < eEnd; p += 256) {
    int2 pr = pairs[p];
    int pos = atomicAdd(&cur[pr.y - nodeBase], 1);
    csr_src[pos] = pr.x;
  }
}

// ---------------- graph boundaries (batch is sorted) ----------------

__global__ void k_starts(const int* __restrict__ batch, int* __restrict__ start) {
  int i = blockIdx.x * blockDim.x + threadIdx.x;
  if (i >= NN) return;
  int b = batch[i];
  int prev = (i == 0) ? -1 : batch[i - 1];
  for (int g = prev + 1; g <= b; ++g) start[g] = i;
  if (i == NN - 1) {
    for (int g = b + 1; g <= NG; ++g) start[g] = NN;
  }
}

// ---------------- GEMM: Out[r][c] = dinv[r] * sum_k A[r][k] * W[k][c] ----------------

#define GR 96
#define LDA 129

__global__ __launch_bounds__(256) void k_gemm(const float* __restrict__ A,
                                              const float* __restrict__ W,
                                              const float* __restrict__ dinv,
                                              float* __restrict__ Out) {
  __shared__ float Al[GR * LDA];
  int rowBase = blockIdx.x * GR;
  int tid = threadIdx.x;

#pragma unroll
  for (int p = 0; p < 12; ++p) {
    int idx = p * 256 + tid;
    int r = idx >> 5;
    int c4 = (idx & 31) * 4;
    int gr = rowBase + r;
    float4 v = {0.f, 0.f, 0.f, 0.f};
    if (gr < NN) v = *(const float4*)(A + (size_t)gr * DH + c4);
    float* dstl = &Al[r * LDA + c4];
    dstl[0] = v.x; dstl[1] = v.y; dstl[2] = v.z; dstl[3] = v.w;
  }
  __syncthreads();

  int tx = tid & 15;
  int ty = tid >> 4;

  float acc[6][8];
#pragma unroll
  for (int i = 0; i < 6; ++i)
#pragma unroll
    for (int j = 0; j < 8; ++j) acc[i][j] = 0.f;

  const float* Wp = W + tx * 8;
#pragma unroll 4
  for (int k = 0; k < DH; ++k) {
    float4 w0 = *(const float4*)(Wp + k * DH);
    float4 w1 = *(const float4*)(Wp + k * DH + 4);
    float wv[8] = {w0.x, w0.y, w0.z, w0.w, w1.x, w1.y, w1.z, w1.w};
#pragma unroll
    for (int i = 0; i < 6; ++i) {
      float a = Al[(ty * 6 + i) * LDA + k];
#pragma unroll
      for (int j = 0; j < 8; ++j) acc[i][j] = fmaf(a, wv[j], acc[i][j]);
    }
  }

#pragma unroll
  for (int i = 0; i < 6; ++i) {
    int r = rowBase + ty * 6 + i;
    if (r < NN) {
      float dv = dinv[r];
      float4 o0 = {acc[i][0] * dv, acc[i][1] * dv, acc[i][2] * dv, acc[i][3] * dv};
      float4 o1 = {acc[i][4] * dv, acc[i][5] * dv, acc[i][6] * dv, acc[i][7] * dv};
      *(float4*)(Out + (size_t)r * DH + tx * 8) = o0;
      *(float4*)(Out + (size_t)r * DH + tx * 8 + 4) = o1;
    }
  }
}

// ---------------- aggregation ----------------

__global__ __launch_bounds__(256) void k_aggregate(const float* __restrict__ hs,
                                                   const int* __restrict__ csr_src,
                                                   const int* __restrict__ offsets,
                                                   const float* __restrict__ dinv,
                                                   const float* __restrict__ bias,
                                                   float* __restrict__ hout) {
  int gid = blockIdx.x * 256 + threadIdx.x;
  int node = gid >> 5;
  int lane4 = (gid & 31) * 4;
  if (node >= NN) return;
  int s = offsets[node];
  int e = offsets[node + 1];

  const float4 self = *(const float4*)(hs + (size_t)node * DH + lane4);
  float ax = self.x, ay = self.y, az = self.z, aw = self.w;

  int p = s;
  for (; p + 1 < e; p += 2) {
    int s0 = csr_src[p];
    int s1 = csr_src[p + 1];
    float4 v0 = *(const float4*)(hs + (size_t)s0 * DH + lane4);
    float4 v1 = *(const float4*)(hs + (size_t)s1 * DH + lane4);
    ax += v0.x + v1.x; ay += v0.y + v1.y; az += v0.z + v1.z; aw += v0.w + v1.w;
  }
  if (p < e) {
    int s0 = csr_src[p];
    float4 v0 = *(const float4*)(hs + (size_t)s0 * DH + lane4);
    ax += v0.x; ay += v0.y; az += v0.z; aw += v0.w;
  }

  float dv = dinv[node];
  float4 b4 = *(const float4*)(bias + lane4);
  float4 r;
  r.x = fmaxf(fmaf(ax, dv, b4.x), 0.f);
  r.y = fmaxf(fmaf(ay, dv, b4.y), 0.f);
  r.z = fmaxf(fmaf(az, dv, b4.z), 0.f);
  r.w = fmaxf(fmaf(aw, dv, b4.w), 0.f);
  *(float4*)(hout + (size_t)node * DH + lane4) = r;
}

// ---------------- pooling ----------------

__global__ void k_pool(const float* __restrict__ h, const int* __restrict__ start,
                       float* __restrict__ pooled, int colOff) {
  int g = blockIdx.x;
  int slice = blockIdx.y;
  int t = threadIdx.x;  // 128
  int s0 = start[g], s1 = start[g + 1];
  int len = s1 - s0;
  int per = (len + 7) >> 3;
  int a = s0 + slice * per;
  int b = a + per;
  if (b > s1) b = s1;
  float acc = 0.f;
  for (int i = a; i < b; ++i) acc += h[(size_t)i * DH + t];
  if (per > 0) atomicAdd(&pooled[g * (3 * DH) + colOff + t], acc);
}

// ---------------- head ----------------

__global__ __launch_bounds__(128) void k_head(const float* __restrict__ pooled,
                                              const int* __restrict__ start,
                                              const float* __restrict__ l1w,
                                              const float* __restrict__ l1b,
                                              const float* __restrict__ l2w,
                                              const float* __restrict__ l2b,
                                              float* __restrict__ out) {
  __shared__ float pr[3 * DH];
  __shared__ float grow[DH];
  __shared__ float lg[16];
  int g = blockIdx.x, t = threadIdx.x;
  float cnt = (float)(start[g + 1] - start[g]);
  float inv = 1.0f / fmaxf(cnt, 1.0f);
  for (int k = t; k < 3 * DH; k += 128) pr[k] = pooled[g * (3 * DH) + k] * inv;
  __syncthreads();
  float acc = l1b[t];
  for (int k = 0; k < 3 * DH; ++k) acc = fmaf(pr[k], l1w[k * DH + t], acc);
  grow[t] = fmaxf(acc, 0.f);
  __syncthreads();
  if (t < 10) {
    float a = l2b[t];
    for (int k = 0; k < DH; ++k) a = fmaf(grow[k], l2w[k * 10 + t], a);
    lg[t] = a;
  }
  __syncthreads();
  if (t < 10) {
    float m = lg[0];
    for (int i = 1; i < 10; ++i) m = fmaxf(m, lg[i]);
    float sum = 0.f;
    for (int i = 0; i < 10; ++i) sum += expf(lg[i] - m);
    out[g * 10 + t] = lg[t] - m - logf(sum);
  }
}

// ---------------- launch ----------------

extern "C" void kernel_launch(void* const* d_in, const int* in_sizes, int n_in,
                              void* d_out, int out_size, void* d_ws, size_t ws_size,
                              hipStream_t stream) {
  const float* x = (const float*)d_in[0];
  const int* ei = (const int*)d_in[1];
  const int* esrc = ei;
  const int* edst = ei + NE;
  const int* batch = (const int*)d_in[2];
  const float* W[3] = {(const float*)d_in[4], (const float*)d_in[6], (const float*)d_in[8]};
  const float* B[3] = {(const float*)d_in[5], (const float*)d_in[7], (const float*)d_in[9]};
  const float* l1w = (const float*)d_in[10];
  const float* l1b = (const float*)d_in[11];
  const float* l2w = (const float*)d_in[12];
  const float* l2b = (const float*)d_in[13];
  float* out = (float*)d_out;

  char* ws = (char*)d_ws;
  size_t off = 0;
  auto alloc = [&](size_t bytes) {
    char* p = ws + off;
    off = (off + bytes + 255) & ~(size_t)255;
    return p;
  };
  int* counts = (int*)alloc((size_t)NN * 4);
  float* dinv = (float*)alloc((size_t)NN * 4);
  int* partial = (int*)alloc((size_t)NN * 4);
  int* blockSums = (int*)alloc(512 * 4);
  int* offsets = (int*)alloc((size_t)(NN + 1) * 4);
  int* csr_src = (int*)alloc((size_t)NE * 4);
  int* start = (int*)alloc((NG + 1) * 4);
  float* pooled = (float*)alloc((size_t)NG * 3 * DH * 4);
  float* bufA = (float*)alloc((size_t)NN * DH * 4);  // hs (scaled GEMM out)
  float* bufB = (float*)alloc((size_t)NN * DH * 4);  // h (post-aggregate)

  // CSR-build scratch aliased onto bufA/bufB (only used before the layer loop)
  int2* pairs = (int2*)bufA;                    // NE * 8B = 12.8 MB <= 51.2 MB
  int* hist = (int*)bufB;                       // NBUCK * NBLK_BIN * 4 = 200 KB

  hipMemsetAsync(counts, 0, (size_t)NN * 4, stream);
  hipMemsetAsync(pooled, 0, (size_t)NG * 3 * DH * 4, stream);

  k_count<<<(NE + 255) / 256, 256, 0, stream>>>(edst, counts);
  k_dinv<<<(NN + 255) / 256, 256, 0, stream>>>(counts, dinv);
  k_scan1<<<NBLK_SCAN, 256, 0, stream>>>(counts, partial, blockSums);
  k_scan2<<<1, 512, 0, stream>>>(blockSums);
  k_scan3<<<(NN + 255) / 256, 256, 0, stream>>>(partial, blockSums, offsets);
  k_binhist<<<NBLK_BIN, 256, 0, stream>>>(edst, hist);
  k_binscan<<<NBUCK, 256, 0, stream>>>(hist, offsets);
  k_binplace<<<NBLK_BIN, 256, 0, stream>>>(esrc, edst, hist, pairs);
  k_place<<<(NN + 1023) / 1024, 256, 0, stream>>>(pairs, offsets, csr_src);
  k_starts<<<(NN + 255) / 256, 256, 0, stream>>>(batch, start);

  const float* gin = x;
  for (int L = 0; L < 3; ++L) {
    k_gemm<<<(NN + GR - 1) / GR, 256, 0, stream>>>(gin, W[L], dinv, bufA);
    k_aggregate<<<(NN * 32) / 256, 256, 0, stream>>>(bufA, csr_src, offsets, dinv, B[L], bufB);
    k_pool<<<dim3(NG, 8), 128, 0, stream>>>(bufB, start, pooled, L * DH);
    gin = bufB;
  }

  k_head<<<NG, 128, 0, stream>>>(pooled, start, l1w, l1b, l2w, l2b, out);
}

// Round 3
// 648.454 us; speedup vs baseline: 1.5823x; 1.4898x over previous
//
#include <hip/hip_runtime.h>

#define NN 100000
#define NE 1600000
#define DH 128
#define NG 64

// CSR build parameters
#define NBUCKU 98          // ceil(NN/1024) buckets, bucket = dst >> 10
#define EPB 4096           // edges per binning block
#define NBLK_BIN 391       // ceil(NE/EPB)

typedef __attribute__((ext_vector_type(4))) _Float16 half4;
typedef __attribute__((ext_vector_type(8))) _Float16 half8;

// ---------------- CSR build: two-level counting sort ----------------

// Pass A: per-(block, bucket) histogram.
__global__ __launch_bounds__(256) void k_binhist(const int* __restrict__ dst,
                                                 int* __restrict__ hist) {
  __shared__ int h[NBUCKU];
  if (threadIdx.x < NBUCKU) h[threadIdx.x] = 0;
  __syncthreads();
  int base = blockIdx.x * EPB;
#pragma unroll
  for (int i = 0; i < EPB / 256; ++i) {
    int e = base + i * 256 + threadIdx.x;
    if (e < NE) atomicAdd(&h[dst[e] >> 10], 1);
  }
  __syncthreads();
  if (threadIdx.x < NBUCKU)
    hist[threadIdx.x * NBLK_BIN + blockIdx.x] = h[threadIdx.x];
}

// Bucket totals (one block per bucket).
__global__ __launch_bounds__(256) void k_bucktot(const int* __restrict__ hist,
                                                 int* __restrict__ tot) {
  __shared__ int red[256];
  int b = blockIdx.x, t = threadIdx.x;
  int s = 0;
  for (int i = t; i < NBLK_BIN; i += 256) s += hist[b * NBLK_BIN + i];
  red[t] = s;
  __syncthreads();
  for (int off = 128; off > 0; off >>= 1) {
    if (t < off) red[t] += red[t + off];
    __syncthreads();
  }
  if (t == 0) tot[b] = red[0];
}

// Exclusive scan of bucket totals -> bucketBase[0..NBUCKU].
__global__ __launch_bounds__(128) void k_buckscan(const int* __restrict__ tot,
                                                  int* __restrict__ bucketBase) {
  __shared__ int v[128];
  int t = threadIdx.x;
  v[t] = (t < NBUCKU) ? tot[t] : 0;
  __syncthreads();
  for (int off = 1; off < 128; off <<= 1) {
    int x = (t >= off) ? v[t - off] : 0;
    __syncthreads();
    v[t] += x;
    __syncthreads();
  }
  bucketBase[t + 1] = v[t];  // inclusive -> base[t+1]
  if (t == 0) bucketBase[0] = 0;
}

// Per-bucket exclusive scan across blocks, seeded with bucket base.
__global__ __launch_bounds__(256) void k_binscan(int* __restrict__ hist,
                                                 const int* __restrict__ bucketBase) {
  __shared__ int v[NBLK_BIN + 1];
  int b = blockIdx.x;
  for (int i = threadIdx.x; i < NBLK_BIN; i += 256)
    v[i] = hist[b * NBLK_BIN + i];
  __syncthreads();
  if (threadIdx.x == 0) {
    int running = bucketBase[b];
    for (int i = 0; i < NBLK_BIN; ++i) {
      int t = v[i];
      v[i] = running;
      running += t;
    }
  }
  __syncthreads();
  for (int i = threadIdx.x; i < NBLK_BIN; i += 256)
    hist[b * NBLK_BIN + i] = v[i];
}

// Pass B: place (src,dst) pairs into bucket-major regions.
__global__ __launch_bounds__(256) void k_binplace(const int* __restrict__ src,
                                                  const int* __restrict__ dst,
                                                  const int* __restrict__ hist,
                                                  int2* __restrict__ pairs) {
  __shared__ int cur[NBUCKU];
  if (threadIdx.x < NBUCKU)
    cur[threadIdx.x] = hist[threadIdx.x * NBLK_BIN + blockIdx.x];
  __syncthreads();
  int base = blockIdx.x * EPB;
#pragma unroll
  for (int i = 0; i < EPB / 256; ++i) {
    int e = base + i * 256 + threadIdx.x;
    if (e < NE) {
      int d = dst[e];
      int q = atomicAdd(&cur[d >> 10], 1);
      pairs[q] = make_int2(src[e], d);
    }
  }
}

// Final: one block per bucket. Pass 1: LDS per-node counts -> scan -> offsets,
// dinv. Pass 2: place srcs into exact CSR slots (bucket-private writes).
__global__ __launch_bounds__(256) void k_place(const int2* __restrict__ pairs,
                                               const int* __restrict__ bucketBase,
                                               int* __restrict__ offsets,
                                               float* __restrict__ dinv,
                                               int* __restrict__ csr_src) {
  __shared__ int cnt[1024];
  __shared__ int tsum[256];
  int b = blockIdx.x, t = threadIdx.x;
  int nodeBase = b << 10;
  for (int i = t; i < 1024; i += 256) cnt[i] = 0;
  __syncthreads();
  int pStart = bucketBase[b], pEnd = bucketBase[b + 1];
  for (int p = pStart + t; p < pEnd; p += 256)
    atomicAdd(&cnt[pairs[p].y - nodeBase], 1);
  __syncthreads();
  int c0 = cnt[t * 4], c1 = cnt[t * 4 + 1], c2 = cnt[t * 4 + 2], c3 = cnt[t * 4 + 3];
  tsum[t] = c0 + c1 + c2 + c3;
  __syncthreads();
  for (int off = 1; off < 256; off <<= 1) {
    int v = (t >= off) ? tsum[t - off] : 0;
    __syncthreads();
    tsum[t] += v;
    __syncthreads();
  }
  int base = pStart + ((t > 0) ? tsum[t - 1] : 0);
  int e0 = base, e1 = base + c0, e2 = e1 + c1, e3 = e2 + c2;
  __syncthreads();  // all cnt reads done; safe to overwrite
  cnt[t * 4] = e0; cnt[t * 4 + 1] = e1; cnt[t * 4 + 2] = e2; cnt[t * 4 + 3] = e3;
  int g = nodeBase + t * 4;
  if (g < NN)     { offsets[g] = e0;     dinv[g] = rsqrtf((float)c0 + 1.f); }
  if (g + 1 < NN) { offsets[g + 1] = e1; dinv[g + 1] = rsqrtf((float)c1 + 1.f); }
  if (g + 2 < NN) { offsets[g + 2] = e2; dinv[g + 2] = rsqrtf((float)c2 + 1.f); }
  if (g + 3 < NN) { offsets[g + 3] = e3; dinv[g + 3] = rsqrtf((float)c3 + 1.f); }
  if (b == NBUCKU - 1 && t == 0) offsets[NN] = pEnd;
  __syncthreads();
  for (int p = pStart + t; p < pEnd; p += 256) {
    int2 pr = pairs[p];
    int pos = atomicAdd(&cnt[pr.y - nodeBase], 1);
    csr_src[pos] = pr.x;
  }
}

// ---------------- graph boundaries (batch sorted) ----------------

__global__ void k_starts(const int* __restrict__ batch, int* __restrict__ start) {
  int i = blockIdx.x * blockDim.x + threadIdx.x;
  if (i >= NN) return;
  int b = batch[i];
  int prev = (i == 0) ? -1 : batch[i - 1];
  for (int g = prev + 1; g <= b; ++g) start[g] = i;
  if (i == NN - 1) {
    for (int g = b + 1; g <= NG; ++g) start[g] = NN;
  }
}

// ---------------- GEMM: OutH[r][c] = fp16( dinv[r] * sum_k A[r][k]*W[k][c] ) ---

#define GR 96
#define LDA 129

__global__ __launch_bounds__(256) void k_gemm(const float* __restrict__ A,
                                              const float* __restrict__ W,
                                              const float* __restrict__ dinv,
                                              _Float16* __restrict__ OutH) {
  __shared__ float Al[GR * LDA];
  int rowBase = blockIdx.x * GR;
  int tid = threadIdx.x;

#pragma unroll
  for (int p = 0; p < 12; ++p) {
    int idx = p * 256 + tid;
    int r = idx >> 5;
    int c4 = (idx & 31) * 4;
    int gr = rowBase + r;
    float4 v = {0.f, 0.f, 0.f, 0.f};
    if (gr < NN) v = *(const float4*)(A + (size_t)gr * DH + c4);
    float* dstl = &Al[r * LDA + c4];
    dstl[0] = v.x; dstl[1] = v.y; dstl[2] = v.z; dstl[3] = v.w;
  }
  __syncthreads();

  int tx = tid & 15;
  int ty = tid >> 4;

  float acc[6][8];
#pragma unroll
  for (int i = 0; i < 6; ++i)
#pragma unroll
    for (int j = 0; j < 8; ++j) acc[i][j] = 0.f;

  const float* Wp = W + tx * 8;
#pragma unroll 4
  for (int k = 0; k < DH; ++k) {
    float4 w0 = *(const float4*)(Wp + k * DH);
    float4 w1 = *(const float4*)(Wp + k * DH + 4);
    float wv[8] = {w0.x, w0.y, w0.z, w0.w, w1.x, w1.y, w1.z, w1.w};
#pragma unroll
    for (int i = 0; i < 6; ++i) {
      float a = Al[(ty * 6 + i) * LDA + k];
#pragma unroll
      for (int j = 0; j < 8; ++j) acc[i][j] = fmaf(a, wv[j], acc[i][j]);
    }
  }

#pragma unroll
  for (int i = 0; i < 6; ++i) {
    int r = rowBase + ty * 6 + i;
    if (r < NN) {
      float dv = dinv[r];
      half8 o;
#pragma unroll
      for (int j = 0; j < 8; ++j) o[j] = (_Float16)(acc[i][j] * dv);
      *(half8*)(OutH + (size_t)r * DH + tx * 8) = o;
    }
  }
}

// ---------------- aggregation + fused pooling ----------------
// 32 threads per node (4 dims each), 8 nodes per 256-thread block.
// h[i] = relu(dinv[i]*(sum_{e->i} hs[src] + hs[i]) + b); pooled[batch[i]] += h[i].

__global__ __launch_bounds__(256) void k_aggregate(const _Float16* __restrict__ hs,
                                                   const int* __restrict__ csr_src,
                                                   const int* __restrict__ offsets,
                                                   const float* __restrict__ dinv,
                                                   const float* __restrict__ bias,
                                                   const int* __restrict__ batch,
                                                   float* __restrict__ hout,
                                                   float* __restrict__ pooled,
                                                   int colOff) {
  __shared__ float stage[8][DH];
  int tid = threadIdx.x;
  int gid = blockIdx.x * 256 + tid;
  int node = gid >> 5;          // exactly NN nodes: 12500 blocks * 8
  int sub = tid >> 5;           // node slot within block (0..7)
  int lane4 = (gid & 31) * 4;
  int s = offsets[node];
  int e = offsets[node + 1];

  const half4 self = *(const half4*)(hs + (size_t)node * DH + lane4);
  float ax = (float)self[0], ay = (float)self[1], az = (float)self[2], aw = (float)self[3];

  int p = s;
  for (; p + 1 < e; p += 2) {
    int s0 = csr_src[p];
    int s1 = csr_src[p + 1];
    half4 v0 = *(const half4*)(hs + (size_t)s0 * DH + lane4);
    half4 v1 = *(const half4*)(hs + (size_t)s1 * DH + lane4);
    ax += (float)v0[0] + (float)v1[0];
    ay += (float)v0[1] + (float)v1[1];
    az += (float)v0[2] + (float)v1[2];
    aw += (float)v0[3] + (float)v1[3];
  }
  if (p < e) {
    int s0 = csr_src[p];
    half4 v0 = *(const half4*)(hs + (size_t)s0 * DH + lane4);
    ax += (float)v0[0]; ay += (float)v0[1]; az += (float)v0[2]; aw += (float)v0[3];
  }

  float dv = dinv[node];
  float4 b4 = *(const float4*)(bias + lane4);
  float4 r;
  r.x = fmaxf(fmaf(ax, dv, b4.x), 0.f);
  r.y = fmaxf(fmaf(ay, dv, b4.y), 0.f);
  r.z = fmaxf(fmaf(az, dv, b4.z), 0.f);
  r.w = fmaxf(fmaf(aw, dv, b4.w), 0.f);
  *(float4*)(hout + (size_t)node * DH + lane4) = r;

  // fused mean-pool accumulation (batch is sorted; blocks rarely straddle graphs)
  int nodeFirst = blockIdx.x * 8;
  int gFirst = batch[nodeFirst];
  int gLast = batch[nodeFirst + 7];
  if (gFirst == gLast) {
    *(float4*)&stage[sub][lane4] = r;
    __syncthreads();
    if (tid < DH) {
      float ssum = 0.f;
#pragma unroll
      for (int w = 0; w < 8; ++w) ssum += stage[w][tid];
      atomicAdd(&pooled[gFirst * (3 * DH) + colOff + tid], ssum);
    }
  } else {
    int g = batch[node];
    float* pp = &pooled[g * (3 * DH) + colOff + lane4];
    atomicAdd(pp + 0, r.x);
    atomicAdd(pp + 1, r.y);
    atomicAdd(pp + 2, r.z);
    atomicAdd(pp + 3, r.w);
  }
}

// ---------------- head ----------------

__global__ __launch_bounds__(128) void k_head(const float* __restrict__ pooled,
                                              const int* __restrict__ start,
                                              const float* __restrict__ l1w,
                                              const float* __restrict__ l1b,
                                              const float* __restrict__ l2w,
                                              const float* __restrict__ l2b,
                                              float* __restrict__ out) {
  __shared__ float pr[3 * DH];
  __shared__ float grow[DH];
  __shared__ float lg[16];
  int g = blockIdx.x, t = threadIdx.x;
  float cnt = (float)(start[g + 1] - start[g]);
  float inv = 1.0f / fmaxf(cnt, 1.0f);
  for (int k = t; k < 3 * DH; k += 128) pr[k] = pooled[g * (3 * DH) + k] * inv;
  __syncthreads();
  float acc = l1b[t];
  for (int k = 0; k < 3 * DH; ++k) acc = fmaf(pr[k], l1w[k * DH + t], acc);
  grow[t] = fmaxf(acc, 0.f);
  __syncthreads();
  if (t < 10) {
    float a = l2b[t];
    for (int k = 0; k < DH; ++k) a = fmaf(grow[k], l2w[k * 10 + t], a);
    lg[t] = a;
  }
  __syncthreads();
  if (t < 10) {
    float m = lg[0];
    for (int i = 1; i < 10; ++i) m = fmaxf(m, lg[i]);
    float sum = 0.f;
    for (int i = 0; i < 10; ++i) sum += expf(lg[i] - m);
    out[g * 10 + t] = lg[t] - m - logf(sum);
  }
}

// ---------------- launch ----------------

extern "C" void kernel_launch(void* const* d_in, const int* in_sizes, int n_in,
                              void* d_out, int out_size, void* d_ws, size_t ws_size,
                              hipStream_t stream) {
  const float* x = (const float*)d_in[0];
  const int* ei = (const int*)d_in[1];
  const int* esrc = ei;
  const int* edst = ei + NE;
  const int* batch = (const int*)d_in[2];
  const float* W[3] = {(const float*)d_in[4], (const float*)d_in[6], (const float*)d_in[8]};
  const float* B[3] = {(const float*)d_in[5], (const float*)d_in[7], (const float*)d_in[9]};
  const float* l1w = (const float*)d_in[10];
  const float* l1b = (const float*)d_in[11];
  const float* l2w = (const float*)d_in[12];
  const float* l2b = (const float*)d_in[13];
  float* out = (float*)d_out;

  char* ws = (char*)d_ws;
  size_t off = 0;
  auto alloc = [&](size_t bytes) {
    char* p = ws + off;
    off = (off + bytes + 255) & ~(size_t)255;
    return p;
  };
  int* offsets = (int*)alloc((size_t)(NN + 1) * 4);
  float* dinv = (float*)alloc((size_t)NN * 4);
  int* csr_src = (int*)alloc((size_t)NE * 4);
  int* start = (int*)alloc((NG + 1) * 4);
  float* pooled = (float*)alloc((size_t)NG * 3 * DH * 4);
  int* tot = (int*)alloc(128 * 4);
  int* bucketBase = (int*)alloc(132 * 4);
  _Float16* hsh = (_Float16*)alloc((size_t)NN * DH * 2);  // fp16 GEMM out (gather buf)
  float* bufB = (float*)alloc((size_t)NN * DH * 4);       // aggregate out / next GEMM in

  // CSR-build scratch aliased onto layer buffers (used strictly before the loop)
  int* hist = (int*)hsh;        // 98*391*4 = 153 KB <= 25.6 MB
  int2* pairs = (int2*)bufB;    // 12.8 MB <= 51.2 MB

  hipMemsetAsync(pooled, 0, (size_t)NG * 3 * DH * 4, stream);

  k_binhist<<<NBLK_BIN, 256, 0, stream>>>(edst, hist);
  k_bucktot<<<NBUCKU, 256, 0, stream>>>(hist, tot);
  k_buckscan<<<1, 128, 0, stream>>>(tot, bucketBase);
  k_binscan<<<NBUCKU, 256, 0, stream>>>(hist, bucketBase);
  k_binplace<<<NBLK_BIN, 256, 0, stream>>>(esrc, edst, hist, pairs);
  k_place<<<NBUCKU, 256, 0, stream>>>(pairs, bucketBase, offsets, dinv, csr_src);
  k_starts<<<(NN + 255) / 256, 256, 0, stream>>>(batch, start);

  const float* gin = x;
  for (int L = 0; L < 3; ++L) {
    k_gemm<<<(NN + GR - 1) / GR, 256, 0, stream>>>(gin, W[L], dinv, hsh);
    k_aggregate<<<(NN * 32) / 256, 256, 0, stream>>>(hsh, csr_src, offsets, dinv, B[L],
                                                     batch, bufB, pooled, L * DH);
    gin = bufB;
  }

  k_head<<<NG, 128, 0, stream>>>(pooled, start, l1w, l1b, l2w, l2b, out);
}

// Round 4
// 509.163 us; speedup vs baseline: 2.0152x; 1.2736x over previous
//
#include <hip/hip_runtime.h>

#define NN 100000
#define NE 1600000
#define DH 128
#define NG 64

// CSR build parameters
#define NBUCKU 98          // ceil(NN/1024) buckets, bucket = dst >> 10
#define EPB 4096           // edges per binning block
#define NBLK_BIN 391       // ceil(NE/EPB)

#define LDH 136            // padded halves per LDS row (stride 68 dwords -> balanced banks)

typedef __attribute__((ext_vector_type(4))) _Float16 half4;
typedef __attribute__((ext_vector_type(8))) _Float16 half8;
typedef __attribute__((ext_vector_type(4))) float f32x4;

// ---------------- CSR build: two-level counting sort ----------------

__global__ __launch_bounds__(256) void k_binhist(const int* __restrict__ dst,
                                                 int* __restrict__ hist) {
  __shared__ int h[NBUCKU];
  if (threadIdx.x < NBUCKU) h[threadIdx.x] = 0;
  __syncthreads();
  int base = blockIdx.x * EPB;
#pragma unroll
  for (int i = 0; i < EPB / 256; ++i) {
    int e = base + i * 256 + threadIdx.x;
    if (e < NE) atomicAdd(&h[dst[e] >> 10], 1);
  }
  __syncthreads();
  if (threadIdx.x < NBUCKU)
    hist[threadIdx.x * NBLK_BIN + blockIdx.x] = h[threadIdx.x];
}

__global__ __launch_bounds__(256) void k_bucktot(const int* __restrict__ hist,
                                                 int* __restrict__ tot) {
  __shared__ int red[256];
  int b = blockIdx.x, t = threadIdx.x;
  int s = 0;
  for (int i = t; i < NBLK_BIN; i += 256) s += hist[b * NBLK_BIN + i];
  red[t] = s;
  __syncthreads();
  for (int off = 128; off > 0; off >>= 1) {
    if (t < off) red[t] += red[t + off];
    __syncthreads();
  }
  if (t == 0) tot[b] = red[0];
}

__global__ __launch_bounds__(128) void k_buckscan(const int* __restrict__ tot,
                                                  int* __restrict__ bucketBase) {
  __shared__ int v[128];
  int t = threadIdx.x;
  v[t] = (t < NBUCKU) ? tot[t] : 0;
  __syncthreads();
  for (int off = 1; off < 128; off <<= 1) {
    int x = (t >= off) ? v[t - off] : 0;
    __syncthreads();
    v[t] += x;
    __syncthreads();
  }
  bucketBase[t + 1] = v[t];
  if (t == 0) bucketBase[0] = 0;
}

__global__ __launch_bounds__(256) void k_binscan(int* __restrict__ hist,
                                                 const int* __restrict__ bucketBase) {
  __shared__ int v[NBLK_BIN + 1];
  int b = blockIdx.x;
  for (int i = threadIdx.x; i < NBLK_BIN; i += 256)
    v[i] = hist[b * NBLK_BIN + i];
  __syncthreads();
  if (threadIdx.x == 0) {
    int running = bucketBase[b];
    for (int i = 0; i < NBLK_BIN; ++i) {
      int t = v[i];
      v[i] = running;
      running += t;
    }
  }
  __syncthreads();
  for (int i = threadIdx.x; i < NBLK_BIN; i += 256)
    hist[b * NBLK_BIN + i] = v[i];
}

__global__ __launch_bounds__(256) void k_binplace(const int* __restrict__ src,
                                                  const int* __restrict__ dst,
                                                  const int* __restrict__ hist,
                                                  int2* __restrict__ pairs) {
  __shared__ int cur[NBUCKU];
  if (threadIdx.x < NBUCKU)
    cur[threadIdx.x] = hist[threadIdx.x * NBLK_BIN + blockIdx.x];
  __syncthreads();
  int base = blockIdx.x * EPB;
#pragma unroll
  for (int i = 0; i < EPB / 256; ++i) {
    int e = base + i * 256 + threadIdx.x;
    if (e < NE) {
      int d = dst[e];
      int q = atomicAdd(&cur[d >> 10], 1);
      pairs[q] = make_int2(src[e], d);
    }
  }
}

__global__ __launch_bounds__(256) void k_place(const int2* __restrict__ pairs,
                                               const int* __restrict__ bucketBase,
                                               int* __restrict__ offsets,
                                               float* __restrict__ dinv,
                                               int* __restrict__ csr_src) {
  __shared__ int cnt[1024];
  __shared__ int tsum[256];
  int b = blockIdx.x, t = threadIdx.x;
  int nodeBase = b << 10;
  for (int i = t; i < 1024; i += 256) cnt[i] = 0;
  __syncthreads();
  int pStart = bucketBase[b], pEnd = bucketBase[b + 1];
  for (int p = pStart + t; p < pEnd; p += 256)
    atomicAdd(&cnt[pairs[p].y - nodeBase], 1);
  __syncthreads();
  int c0 = cnt[t * 4], c1 = cnt[t * 4 + 1], c2 = cnt[t * 4 + 2], c3 = cnt[t * 4 + 3];
  tsum[t] = c0 + c1 + c2 + c3;
  __syncthreads();
  for (int off = 1; off < 256; off <<= 1) {
    int v = (t >= off) ? tsum[t - off] : 0;
    __syncthreads();
    tsum[t] += v;
    __syncthreads();
  }
  int base = pStart + ((t > 0) ? tsum[t - 1] : 0);
  int e0 = base, e1 = base + c0, e2 = e1 + c1, e3 = e2 + c2;
  __syncthreads();
  cnt[t * 4] = e0; cnt[t * 4 + 1] = e1; cnt[t * 4 + 2] = e2; cnt[t * 4 + 3] = e3;
  int g = nodeBase + t * 4;
  if (g < NN)     { offsets[g] = e0;     dinv[g] = rsqrtf((float)c0 + 1.f); }
  if (g + 1 < NN) { offsets[g + 1] = e1; dinv[g + 1] = rsqrtf((float)c1 + 1.f); }
  if (g + 2 < NN) { offsets[g + 2] = e2; dinv[g + 2] = rsqrtf((float)c2 + 1.f); }
  if (g + 3 < NN) { offsets[g + 3] = e3; dinv[g + 3] = rsqrtf((float)c3 + 1.f); }
  if (b == NBUCKU - 1 && t == 0) offsets[NN] = pEnd;
  __syncthreads();
  for (int p = pStart + t; p < pEnd; p += 256) {
    int2 pr = pairs[p];
    int pos = atomicAdd(&cnt[pr.y - nodeBase], 1);
    csr_src[pos] = pr.x;
  }
}

// ---------------- graph boundaries ----------------

__global__ void k_starts(const int* __restrict__ batch, int* __restrict__ start) {
  int i = blockIdx.x * blockDim.x + threadIdx.x;
  if (i >= NN) return;
  int b = batch[i];
  int prev = (i == 0) ? -1 : batch[i - 1];
  for (int g = prev + 1; g <= b; ++g) start[g] = i;
  if (i == NN - 1) {
    for (int g = b + 1; g <= NG; ++g) start[g] = NN;
  }
}

// ---------------- W transpose to fp16: Wt[n][k] = W[k][n] ----------------

__global__ __launch_bounds__(128) void k_transW(const float* __restrict__ W,
                                                _Float16* __restrict__ Wt) {
  int n = blockIdx.x;
  int k = threadIdx.x;
  Wt[n * DH + k] = (_Float16)W[k * DH + n];
}

// ---------------- MFMA GEMM: OutH = fp16( dinv[r] * (A @ W) ) ----------------
// 128x128 tile per block (4 waves, 32 rows each), K=128 staged once in LDS.
// mfma_f32_16x16x32_f16: A-frag lane m=lane&15, k=quad*8+j; B-frag n=lane&15;
// C/D: col=lane&15, row=quad*4+reg.

template <bool F32IN>
__global__ __launch_bounds__(256) void k_gemm(const void* __restrict__ Ap,
                                              const _Float16* __restrict__ Wt,
                                              const float* __restrict__ dinv,
                                              _Float16* __restrict__ OutH) {
  __shared__ _Float16 Al[128 * LDH];
  __shared__ _Float16 Wl[128 * LDH];
  int tid = threadIdx.x;
  int rowBase = blockIdx.x * 128;

  if (F32IN) {
    const float* A = (const float*)Ap;
#pragma unroll
    for (int i = 0; i < 16; ++i) {
      int chunk = tid + i * 256;          // 4096 chunks of float4
      int r = chunk >> 5, c = (chunk & 31) * 4;
      int gr = rowBase + r;
      float4 v = {0.f, 0.f, 0.f, 0.f};
      if (gr < NN) v = *(const float4*)(A + (size_t)gr * DH + c);
      half4 h = {(_Float16)v.x, (_Float16)v.y, (_Float16)v.z, (_Float16)v.w};
      *(half4*)&Al[r * LDH + c] = h;
    }
  } else {
    const _Float16* A = (const _Float16*)Ap;
#pragma unroll
    for (int i = 0; i < 8; ++i) {
      int chunk = tid + i * 256;          // 2048 chunks of half8
      int r = chunk >> 4, c = (chunk & 15) * 8;
      int gr = rowBase + r;
      half8 v = {};
      if (gr < NN) v = *(const half8*)(A + (size_t)gr * DH + c);
      *(half8*)&Al[r * LDH + c] = v;
    }
  }
#pragma unroll
  for (int i = 0; i < 8; ++i) {
    int chunk = tid + i * 256;
    int r = chunk >> 4, c = (chunk & 15) * 8;
    *(half8*)&Wl[r * LDH + c] = *(const half8*)(Wt + r * DH + c);
  }
  __syncthreads();

  int wv = tid >> 6;
  int lane = tid & 63;
  int n16 = lane & 15;
  int quad = lane >> 4;

  f32x4 acc[2][8];
#pragma unroll
  for (int mt = 0; mt < 2; ++mt)
#pragma unroll
    for (int ct = 0; ct < 8; ++ct) acc[mt][ct] = (f32x4){0.f, 0.f, 0.f, 0.f};

  const _Float16* a0p = &Al[(wv * 32 + n16) * LDH + quad * 8];
  const _Float16* a1p = a0p + 16 * LDH;
  const _Float16* bp = &Wl[n16 * LDH + quad * 8];

#pragma unroll
  for (int kk = 0; kk < 4; ++kk) {
    half8 af0 = *(const half8*)(a0p + kk * 32);
    half8 af1 = *(const half8*)(a1p + kk * 32);
#pragma unroll
    for (int ct = 0; ct < 8; ++ct) {
      half8 bf = *(const half8*)(bp + (size_t)ct * 16 * LDH + kk * 32);
      acc[0][ct] = __builtin_amdgcn_mfma_f32_16x16x32_f16(af0, bf, acc[0][ct], 0, 0, 0);
      acc[1][ct] = __builtin_amdgcn_mfma_f32_16x16x32_f16(af1, bf, acc[1][ct], 0, 0, 0);
    }
  }

  // epilogue: dinv-scale, fp16, stage into own rows of Al
  float dv[2][4];
#pragma unroll
  for (int mt = 0; mt < 2; ++mt)
#pragma unroll
    for (int r = 0; r < 4; ++r) {
      int gr = rowBase + wv * 32 + mt * 16 + quad * 4 + r;
      dv[mt][r] = (gr < NN) ? dinv[gr] : 0.f;
    }
#pragma unroll
  for (int mt = 0; mt < 2; ++mt)
#pragma unroll
    for (int ct = 0; ct < 8; ++ct)
#pragma unroll
      for (int r = 0; r < 4; ++r)
        Al[(wv * 32 + mt * 16 + quad * 4 + r) * LDH + ct * 16 + n16] =
            (_Float16)(acc[mt][ct][r] * dv[mt][r]);
  __syncthreads();

#pragma unroll
  for (int i = 0; i < 8; ++i) {
    int chunk = tid + i * 256;
    int r = chunk >> 4, c = (chunk & 15) * 8;
    int gr = rowBase + r;
    if (gr < NN)
      *(half8*)(OutH + (size_t)gr * DH + c) = *(const half8*)&Al[r * LDH + c];
  }
}

// ---------------- aggregation + fused pooling ----------------

__global__ __launch_bounds__(256) void k_aggregate(const _Float16* __restrict__ hs,
                                                   const int* __restrict__ csr_src,
                                                   const int* __restrict__ offsets,
                                                   const float* __restrict__ dinv,
                                                   const float* __restrict__ bias,
                                                   const int* __restrict__ batch,
                                                   _Float16* __restrict__ hout,
                                                   float* __restrict__ pooled,
                                                   int colOff, int writeH) {
  __shared__ float stage[8][DH];
  int tid = threadIdx.x;
  int gid = blockIdx.x * 256 + tid;
  int node = gid >> 5;
  int sub = tid >> 5;
  int lane4 = (gid & 31) * 4;
  int s = offsets[node];
  int e = offsets[node + 1];

  const half4 self = *(const half4*)(hs + (size_t)node * DH + lane4);
  float ax = (float)self[0], ay = (float)self[1], az = (float)self[2], aw = (float)self[3];

  int p = s;
  for (; p + 3 < e; p += 4) {
    int s0 = csr_src[p];
    int s1 = csr_src[p + 1];
    int s2 = csr_src[p + 2];
    int s3 = csr_src[p + 3];
    half4 v0 = *(const half4*)(hs + (size_t)s0 * DH + lane4);
    half4 v1 = *(const half4*)(hs + (size_t)s1 * DH + lane4);
    half4 v2 = *(const half4*)(hs + (size_t)s2 * DH + lane4);
    half4 v3 = *(const half4*)(hs + (size_t)s3 * DH + lane4);
    ax += ((float)v0[0] + (float)v1[0]) + ((float)v2[0] + (float)v3[0]);
    ay += ((float)v0[1] + (float)v1[1]) + ((float)v2[1] + (float)v3[1]);
    az += ((float)v0[2] + (float)v1[2]) + ((float)v2[2] + (float)v3[2]);
    aw += ((float)v0[3] + (float)v1[3]) + ((float)v2[3] + (float)v3[3]);
  }
  for (; p < e; ++p) {
    int s0 = csr_src[p];
    half4 v0 = *(const half4*)(hs + (size_t)s0 * DH + lane4);
    ax += (float)v0[0]; ay += (float)v0[1]; az += (float)v0[2]; aw += (float)v0[3];
  }

  float dv = dinv[node];
  float4 b4 = *(const float4*)(bias + lane4);
  float4 r;
  r.x = fmaxf(fmaf(ax, dv, b4.x), 0.f);
  r.y = fmaxf(fmaf(ay, dv, b4.y), 0.f);
  r.z = fmaxf(fmaf(az, dv, b4.z), 0.f);
  r.w = fmaxf(fmaf(aw, dv, b4.w), 0.f);
  if (writeH) {
    half4 rh = {(_Float16)r.x, (_Float16)r.y, (_Float16)r.z, (_Float16)r.w};
    *(half4*)(hout + (size_t)node * DH + lane4) = rh;
  }

  int nodeFirst = blockIdx.x * 8;
  int gFirst = batch[nodeFirst];
  int gLast = batch[nodeFirst + 7];
  if (gFirst == gLast) {
    *(float4*)&stage[sub][lane4] = r;
    __syncthreads();
    if (tid < DH) {
      float ssum = 0.f;
#pragma unroll
      for (int w = 0; w < 8; ++w) ssum += stage[w][tid];
      atomicAdd(&pooled[gFirst * (3 * DH) + colOff + tid], ssum);
    }
  } else {
    int g = batch[node];
    float* pp = &pooled[g * (3 * DH) + colOff + lane4];
    atomicAdd(pp + 0, r.x);
    atomicAdd(pp + 1, r.y);
    atomicAdd(pp + 2, r.z);
    atomicAdd(pp + 3, r.w);
  }
}

// ---------------- head ----------------

__global__ __launch_bounds__(128) void k_head(const float* __restrict__ pooled,
                                              const int* __restrict__ start,
                                              const float* __restrict__ l1w,
                                              const float* __restrict__ l1b,
                                              const float* __restrict__ l2w,
                                              const float* __restrict__ l2b,
                                              float* __restrict__ out) {
  __shared__ float pr[3 * DH];
  __shared__ float grow[DH];
  __shared__ float lg[16];
  int g = blockIdx.x, t = threadIdx.x;
  float cnt = (float)(start[g + 1] - start[g]);
  float inv = 1.0f / fmaxf(cnt, 1.0f);
  for (int k = t; k < 3 * DH; k += 128) pr[k] = pooled[g * (3 * DH) + k] * inv;
  __syncthreads();
  float acc = l1b[t];
  for (int k = 0; k < 3 * DH; ++k) acc = fmaf(pr[k], l1w[k * DH + t], acc);
  grow[t] = fmaxf(acc, 0.f);
  __syncthreads();
  if (t < 10) {
    float a = l2b[t];
    for (int k = 0; k < DH; ++k) a = fmaf(grow[k], l2w[k * 10 + t], a);
    lg[t] = a;
  }
  __syncthreads();
  if (t < 10) {
    float m = lg[0];
    for (int i = 1; i < 10; ++i) m = fmaxf(m, lg[i]);
    float sum = 0.f;
    for (int i = 0; i < 10; ++i) sum += expf(lg[i] - m);
    out[g * 10 + t] = lg[t] - m - logf(sum);
  }
}

// ---------------- launch ----------------

extern "C" void kernel_launch(void* const* d_in, const int* in_sizes, int n_in,
                              void* d_out, int out_size, void* d_ws, size_t ws_size,
                              hipStream_t stream) {
  const float* x = (const float*)d_in[0];
  const int* ei = (const int*)d_in[1];
  const int* esrc = ei;
  const int* edst = ei + NE;
  const int* batch = (const int*)d_in[2];
  const float* W[3] = {(const float*)d_in[4], (const float*)d_in[6], (const float*)d_in[8]};
  const float* B[3] = {(const float*)d_in[5], (const float*)d_in[7], (const float*)d_in[9]};
  const float* l1w = (const float*)d_in[10];
  const float* l1b = (const float*)d_in[11];
  const float* l2w = (const float*)d_in[12];
  const float* l2b = (const float*)d_in[13];
  float* out = (float*)d_out;

  char* ws = (char*)d_ws;
  size_t off = 0;
  auto alloc = [&](size_t bytes) {
    char* p = ws + off;
    off = (off + bytes + 255) & ~(size_t)255;
    return p;
  };
  int* offsets = (int*)alloc((size_t)(NN + 1) * 4);
  float* dinv = (float*)alloc((size_t)NN * 4);
  int* csr_src = (int*)alloc((size_t)NE * 4);
  int* start = (int*)alloc((NG + 1) * 4);
  float* pooled = (float*)alloc((size_t)NG * 3 * DH * 4);
  int* tot = (int*)alloc(128 * 4);
  int* bucketBase = (int*)alloc(132 * 4);
  _Float16* Wt = (_Float16*)alloc((size_t)DH * DH * 2);
  _Float16* hsh = (_Float16*)alloc((size_t)NN * DH * 2);  // GEMM out (gather buf)
  _Float16* hb = (_Float16*)alloc((size_t)NN * DH * 2);   // aggregate out / next GEMM in

  // CSR-build scratch aliased onto layer buffers (used strictly before the loop)
  int* hist = (int*)hsh;        // 98*391*4 = 153 KB <= 25.6 MB
  int2* pairs = (int2*)hb;      // 12.8 MB <= 25.6 MB

  hipMemsetAsync(pooled, 0, (size_t)NG * 3 * DH * 4, stream);

  k_binhist<<<NBLK_BIN, 256, 0, stream>>>(edst, hist);
  k_bucktot<<<NBUCKU, 256, 0, stream>>>(hist, tot);
  k_buckscan<<<1, 128, 0, stream>>>(tot, bucketBase);
  k_binscan<<<NBUCKU, 256, 0, stream>>>(hist, bucketBase);
  k_binplace<<<NBLK_BIN, 256, 0, stream>>>(esrc, edst, hist, pairs);
  k_place<<<NBUCKU, 256, 0, stream>>>(pairs, bucketBase, offsets, dinv, csr_src);
  k_starts<<<(NN + 255) / 256, 256, 0, stream>>>(batch, start);

  int nGemmBlk = (NN + 127) / 128;
  for (int L = 0; L < 3; ++L) {
    k_transW<<<DH, DH, 0, stream>>>(W[L], Wt);
    if (L == 0)
      k_gemm<true><<<nGemmBlk, 256, 0, stream>>>((const void*)x, Wt, dinv, hsh);
    else
      k_gemm<false><<<nGemmBlk, 256, 0, stream>>>((const void*)hb, Wt, dinv, hsh);
    k_aggregate<<<(NN * 32) / 256, 256, 0, stream>>>(hsh, csr_src, offsets, dinv, B[L],
                                                     batch, hb, pooled, L * DH,
                                                     (L < 2) ? 1 : 0);
  }

  k_head<<<NG, 128, 0, stream>>>(pooled, start, l1w, l1b, l2w, l2b, out);
}

// Round 5
// 439.377 us; speedup vs baseline: 2.3353x; 1.1588x over previous
//
#include <hip/hip_runtime.h>

#define NN 100000
#define NE 1600000
#define DH 128
#define NG 64

// CSR build parameters
#define NBUCKU 98          // ceil(NN/1024) buckets, bucket = dst >> 10
#define EPB 4096           // edges per binning block
#define NBLK_BIN 391       // ceil(NE/EPB)

#define LDH 136            // padded halves per LDS row

typedef __attribute__((ext_vector_type(4))) _Float16 half4;
typedef __attribute__((ext_vector_type(8))) _Float16 half8;
typedef __attribute__((ext_vector_type(4))) float f32x4;

// e5m2 via fp16 bit ops: encode = RNE-round fp16 to top byte; decode = byte<<8.
__device__ inline unsigned int enc8(_Float16 h) {
  unsigned short b = __builtin_bit_cast(unsigned short, h);
  unsigned short r = (unsigned short)(b + 0x7F + ((b >> 8) & 1));
  return (unsigned int)(r >> 8);
}
__device__ inline float dec8(unsigned int byte) {
  return (float)__builtin_bit_cast(_Float16, (unsigned short)(byte << 8));
}

// ---------------- CSR build: two-level counting sort ----------------

__global__ __launch_bounds__(256) void k_binhist(const int* __restrict__ dst,
                                                 int* __restrict__ hist) {
  __shared__ int h[NBUCKU];
  if (threadIdx.x < NBUCKU) h[threadIdx.x] = 0;
  __syncthreads();
  int base = blockIdx.x * EPB;
#pragma unroll
  for (int i = 0; i < EPB / 256; ++i) {
    int e = base + i * 256 + threadIdx.x;
    if (e < NE) atomicAdd(&h[dst[e] >> 10], 1);
  }
  __syncthreads();
  if (threadIdx.x < NBUCKU)
    hist[threadIdx.x * NBLK_BIN + blockIdx.x] = h[threadIdx.x];
}

__global__ __launch_bounds__(256) void k_bucktot(const int* __restrict__ hist,
                                                 int* __restrict__ tot) {
  __shared__ int red[256];
  int b = blockIdx.x, t = threadIdx.x;
  int s = 0;
  for (int i = t; i < NBLK_BIN; i += 256) s += hist[b * NBLK_BIN + i];
  red[t] = s;
  __syncthreads();
  for (int off = 128; off > 0; off >>= 1) {
    if (t < off) red[t] += red[t + off];
    __syncthreads();
  }
  if (t == 0) tot[b] = red[0];
}

__global__ __launch_bounds__(128) void k_buckscan(const int* __restrict__ tot,
                                                  int* __restrict__ bucketBase) {
  __shared__ int v[128];
  int t = threadIdx.x;
  v[t] = (t < NBUCKU) ? tot[t] : 0;
  __syncthreads();
  for (int off = 1; off < 128; off <<= 1) {
    int x = (t >= off) ? v[t - off] : 0;
    __syncthreads();
    v[t] += x;
    __syncthreads();
  }
  bucketBase[t + 1] = v[t];
  if (t == 0) bucketBase[0] = 0;
}

__global__ __launch_bounds__(256) void k_binscan(int* __restrict__ hist,
                                                 const int* __restrict__ bucketBase) {
  __shared__ int v[NBLK_BIN + 1];
  int b = blockIdx.x;
  for (int i = threadIdx.x; i < NBLK_BIN; i += 256)
    v[i] = hist[b * NBLK_BIN + i];
  __syncthreads();
  if (threadIdx.x == 0) {
    int running = bucketBase[b];
    for (int i = 0; i < NBLK_BIN; ++i) {
      int t = v[i];
      v[i] = running;
      running += t;
    }
  }
  __syncthreads();
  for (int i = threadIdx.x; i < NBLK_BIN; i += 256)
    hist[b * NBLK_BIN + i] = v[i];
}

__global__ __launch_bounds__(256) void k_binplace(const int* __restrict__ src,
                                                  const int* __restrict__ dst,
                                                  const int* __restrict__ hist,
                                                  int2* __restrict__ pairs) {
  __shared__ int cur[NBUCKU];
  if (threadIdx.x < NBUCKU)
    cur[threadIdx.x] = hist[threadIdx.x * NBLK_BIN + blockIdx.x];
  __syncthreads();
  int base = blockIdx.x * EPB;
#pragma unroll
  for (int i = 0; i < EPB / 256; ++i) {
    int e = base + i * 256 + threadIdx.x;
    if (e < NE) {
      int d = dst[e];
      int q = atomicAdd(&cur[d >> 10], 1);
      pairs[q] = make_int2(src[e], d);
    }
  }
}

__global__ __launch_bounds__(256) void k_place(const int2* __restrict__ pairs,
                                               const int* __restrict__ bucketBase,
                                               int* __restrict__ offsets,
                                               float* __restrict__ dinv,
                                               int* __restrict__ csr_src) {
  __shared__ int cnt[1024];
  __shared__ int tsum[256];
  int b = blockIdx.x, t = threadIdx.x;
  int nodeBase = b << 10;
  for (int i = t; i < 1024; i += 256) cnt[i] = 0;
  __syncthreads();
  int pStart = bucketBase[b], pEnd = bucketBase[b + 1];
  for (int p = pStart + t; p < pEnd; p += 256)
    atomicAdd(&cnt[pairs[p].y - nodeBase], 1);
  __syncthreads();
  int c0 = cnt[t * 4], c1 = cnt[t * 4 + 1], c2 = cnt[t * 4 + 2], c3 = cnt[t * 4 + 3];
  tsum[t] = c0 + c1 + c2 + c3;
  __syncthreads();
  for (int off = 1; off < 256; off <<= 1) {
    int v = (t >= off) ? tsum[t - off] : 0;
    __syncthreads();
    tsum[t] += v;
    __syncthreads();
  }
  int base = pStart + ((t > 0) ? tsum[t - 1] : 0);
  int e0 = base, e1 = base + c0, e2 = e1 + c1, e3 = e2 + c2;
  __syncthreads();
  cnt[t * 4] = e0; cnt[t * 4 + 1] = e1; cnt[t * 4 + 2] = e2; cnt[t * 4 + 3] = e3;
  int g = nodeBase + t * 4;
  if (g < NN)     { offsets[g] = e0;     dinv[g] = rsqrtf((float)c0 + 1.f); }
  if (g + 1 < NN) { offsets[g + 1] = e1; dinv[g + 1] = rsqrtf((float)c1 + 1.f); }
  if (g + 2 < NN) { offsets[g + 2] = e2; dinv[g + 2] = rsqrtf((float)c2 + 1.f); }
  if (g + 3 < NN) { offsets[g + 3] = e3; dinv[g + 3] = rsqrtf((float)c3 + 1.f); }
  if (b == NBUCKU - 1 && t == 0) offsets[NN] = pEnd;
  __syncthreads();
  for (int p = pStart + t; p < pEnd; p += 256) {
    int2 pr = pairs[p];
    int pos = atomicAdd(&cnt[pr.y - nodeBase], 1);
    csr_src[pos] = pr.x;
  }
}

// ---------------- graph boundaries ----------------

__global__ void k_starts(const int* __restrict__ batch, int* __restrict__ start) {
  int i = blockIdx.x * blockDim.x + threadIdx.x;
  if (i >= NN) return;
  int b = batch[i];
  int prev = (i == 0) ? -1 : batch[i - 1];
  for (int g = prev + 1; g <= b; ++g) start[g] = i;
  if (i == NN - 1) {
    for (int g = b + 1; g <= NG; ++g) start[g] = NN;
  }
}

// ---------------- W transpose to fp16: Wt[n][k] = W[k][n] ----------------

__global__ __launch_bounds__(128) void k_transW(const float* __restrict__ W,
                                                _Float16* __restrict__ Wt) {
  int n = blockIdx.x;
  int k = threadIdx.x;
  Wt[n * DH + k] = (_Float16)W[k * DH + n];
}

// ---------------- MFMA GEMM: Out8 = e5m2( dinv[r] * (A @ W) ) ----------------

template <bool F32IN>
__global__ __launch_bounds__(256) void k_gemm(const void* __restrict__ Ap,
                                              const _Float16* __restrict__ Wt,
                                              const float* __restrict__ dinv,
                                              unsigned char* __restrict__ Out8) {
  __shared__ _Float16 Al[128 * LDH];
  __shared__ _Float16 Wl[128 * LDH];
  int tid = threadIdx.x;
  int rowBase = blockIdx.x * 128;

  if (F32IN) {
    const float* A = (const float*)Ap;
#pragma unroll
    for (int i = 0; i < 16; ++i) {
      int chunk = tid + i * 256;
      int r = chunk >> 5, c = (chunk & 31) * 4;
      int gr = rowBase + r;
      float4 v = {0.f, 0.f, 0.f, 0.f};
      if (gr < NN) v = *(const float4*)(A + (size_t)gr * DH + c);
      half4 h = {(_Float16)v.x, (_Float16)v.y, (_Float16)v.z, (_Float16)v.w};
      *(half4*)&Al[r * LDH + c] = h;
    }
  } else {
    const _Float16* A = (const _Float16*)Ap;
#pragma unroll
    for (int i = 0; i < 8; ++i) {
      int chunk = tid + i * 256;
      int r = chunk >> 4, c = (chunk & 15) * 8;
      int gr = rowBase + r;
      half8 v = {};
      if (gr < NN) v = *(const half8*)(A + (size_t)gr * DH + c);
      *(half8*)&Al[r * LDH + c] = v;
    }
  }
#pragma unroll
  for (int i = 0; i < 8; ++i) {
    int chunk = tid + i * 256;
    int r = chunk >> 4, c = (chunk & 15) * 8;
    *(half8*)&Wl[r * LDH + c] = *(const half8*)(Wt + r * DH + c);
  }
  __syncthreads();

  int wv = tid >> 6;
  int lane = tid & 63;
  int n16 = lane & 15;
  int quad = lane >> 4;

  f32x4 acc[2][8];
#pragma unroll
  for (int mt = 0; mt < 2; ++mt)
#pragma unroll
    for (int ct = 0; ct < 8; ++ct) acc[mt][ct] = (f32x4){0.f, 0.f, 0.f, 0.f};

  const _Float16* a0p = &Al[(wv * 32 + n16) * LDH + quad * 8];
  const _Float16* a1p = a0p + 16 * LDH;
  const _Float16* bp = &Wl[n16 * LDH + quad * 8];

#pragma unroll
  for (int kk = 0; kk < 4; ++kk) {
    half8 af0 = *(const half8*)(a0p + kk * 32);
    half8 af1 = *(const half8*)(a1p + kk * 32);
#pragma unroll
    for (int ct = 0; ct < 8; ++ct) {
      half8 bf = *(const half8*)(bp + (size_t)ct * 16 * LDH + kk * 32);
      acc[0][ct] = __builtin_amdgcn_mfma_f32_16x16x32_f16(af0, bf, acc[0][ct], 0, 0, 0);
      acc[1][ct] = __builtin_amdgcn_mfma_f32_16x16x32_f16(af1, bf, acc[1][ct], 0, 0, 0);
    }
  }

  // epilogue: dinv-scale to fp16, stage into wave-private rows of Al
  float dv[2][4];
#pragma unroll
  for (int mt = 0; mt < 2; ++mt)
#pragma unroll
    for (int r = 0; r < 4; ++r) {
      int gr = rowBase + wv * 32 + mt * 16 + quad * 4 + r;
      dv[mt][r] = (gr < NN) ? dinv[gr] : 0.f;
    }
#pragma unroll
  for (int mt = 0; mt < 2; ++mt)
#pragma unroll
    for (int ct = 0; ct < 8; ++ct)
#pragma unroll
      for (int r = 0; r < 4; ++r)
        Al[(wv * 32 + mt * 16 + quad * 4 + r) * LDH + ct * 16 + n16] =
            (_Float16)(acc[mt][ct][r] * dv[mt][r]);
  __syncthreads();

  // coalesced e5m2 store: 8 bytes per thread-chunk
#pragma unroll
  for (int i = 0; i < 8; ++i) {
    int chunk = tid + i * 256;
    int r = chunk >> 4, c = (chunk & 15) * 8;
    int gr = rowBase + r;
    if (gr < NN) {
      half8 v = *(const half8*)&Al[r * LDH + c];
      unsigned int lo = enc8(v[0]) | (enc8(v[1]) << 8) | (enc8(v[2]) << 16) | (enc8(v[3]) << 24);
      unsigned int hi = enc8(v[4]) | (enc8(v[5]) << 8) | (enc8(v[6]) << 16) | (enc8(v[7]) << 24);
      uint2 st = {lo, hi};
      *(uint2*)(Out8 + (size_t)gr * DH + c) = st;
    }
  }
}

// ---------------- aggregation + fused pooling (e5m2 gather) ----------------

__global__ __launch_bounds__(256) void k_aggregate(const unsigned char* __restrict__ hs8,
                                                   const int* __restrict__ csr_src,
                                                   const int* __restrict__ offsets,
                                                   const float* __restrict__ dinv,
                                                   const float* __restrict__ bias,
                                                   const int* __restrict__ batch,
                                                   _Float16* __restrict__ hout,
                                                   float* __restrict__ pooled,
                                                   int colOff, int writeH) {
  __shared__ float stage[8][DH];
  int tid = threadIdx.x;
  int gid = blockIdx.x * 256 + tid;
  int node = gid >> 5;
  int sub = tid >> 5;
  int lane4 = (gid & 31) * 4;
  int s = offsets[node];
  int e = offsets[node + 1];

  unsigned int us = *(const unsigned int*)(hs8 + (size_t)node * DH + lane4);
  float ax = dec8(us & 0xff), ay = dec8((us >> 8) & 0xff),
        az = dec8((us >> 16) & 0xff), aw = dec8(us >> 24);

  int p = s;
  for (; p + 3 < e; p += 4) {
    int s0 = csr_src[p];
    int s1 = csr_src[p + 1];
    int s2 = csr_src[p + 2];
    int s3 = csr_src[p + 3];
    unsigned int u0 = *(const unsigned int*)(hs8 + (size_t)s0 * DH + lane4);
    unsigned int u1 = *(const unsigned int*)(hs8 + (size_t)s1 * DH + lane4);
    unsigned int u2 = *(const unsigned int*)(hs8 + (size_t)s2 * DH + lane4);
    unsigned int u3 = *(const unsigned int*)(hs8 + (size_t)s3 * DH + lane4);
    ax += (dec8(u0 & 0xff) + dec8(u1 & 0xff)) + (dec8(u2 & 0xff) + dec8(u3 & 0xff));
    ay += (dec8((u0 >> 8) & 0xff) + dec8((u1 >> 8) & 0xff)) +
          (dec8((u2 >> 8) & 0xff) + dec8((u3 >> 8) & 0xff));
    az += (dec8((u0 >> 16) & 0xff) + dec8((u1 >> 16) & 0xff)) +
          (dec8((u2 >> 16) & 0xff) + dec8((u3 >> 16) & 0xff));
    aw += (dec8(u0 >> 24) + dec8(u1 >> 24)) + (dec8(u2 >> 24) + dec8(u3 >> 24));
  }
  for (; p < e; ++p) {
    int s0 = csr_src[p];
    unsigned int u0 = *(const unsigned int*)(hs8 + (size_t)s0 * DH + lane4);
    ax += dec8(u0 & 0xff); ay += dec8((u0 >> 8) & 0xff);
    az += dec8((u0 >> 16) & 0xff); aw += dec8(u0 >> 24);
  }

  float dv = dinv[node];
  float4 b4 = *(const float4*)(bias + lane4);
  float4 r;
  r.x = fmaxf(fmaf(ax, dv, b4.x), 0.f);
  r.y = fmaxf(fmaf(ay, dv, b4.y), 0.f);
  r.z = fmaxf(fmaf(az, dv, b4.z), 0.f);
  r.w = fmaxf(fmaf(aw, dv, b4.w), 0.f);
  if (writeH) {
    half4 rh = {(_Float16)r.x, (_Float16)r.y, (_Float16)r.z, (_Float16)r.w};
    *(half4*)(hout + (size_t)node * DH + lane4) = rh;
  }

  int nodeFirst = blockIdx.x * 8;
  int gFirst = batch[nodeFirst];
  int gLast = batch[nodeFirst + 7];
  if (gFirst == gLast) {
    *(float4*)&stage[sub][lane4] = r;
    __syncthreads();
    if (tid < DH) {
      float ssum = 0.f;
#pragma unroll
      for (int w = 0; w < 8; ++w) ssum += stage[w][tid];
      atomicAdd(&pooled[gFirst * (3 * DH) + colOff + tid], ssum);
    }
  } else {
    int g = batch[node];
    float* pp = &pooled[g * (3 * DH) + colOff + lane4];
    atomicAdd(pp + 0, r.x);
    atomicAdd(pp + 1, r.y);
    atomicAdd(pp + 2, r.z);
    atomicAdd(pp + 3, r.w);
  }
}

// ---------------- head ----------------

__global__ __launch_bounds__(128) void k_head(const float* __restrict__ pooled,
                                              const int* __restrict__ start,
                                              const float* __restrict__ l1w,
                                              const float* __restrict__ l1b,
                                              const float* __restrict__ l2w,
                                              const float* __restrict__ l2b,
                                              float* __restrict__ out) {
  __shared__ float pr[3 * DH];
  __shared__ float grow[DH];
  __shared__ float lg[16];
  int g = blockIdx.x, t = threadIdx.x;
  float cnt = (float)(start[g + 1] - start[g]);
  float inv = 1.0f / fmaxf(cnt, 1.0f);
  for (int k = t; k < 3 * DH; k += 128) pr[k] = pooled[g * (3 * DH) + k] * inv;
  __syncthreads();
  float acc = l1b[t];
  for (int k = 0; k < 3 * DH; ++k) acc = fmaf(pr[k], l1w[k * DH + t], acc);
  grow[t] = fmaxf(acc, 0.f);
  __syncthreads();
  if (t < 10) {
    float a = l2b[t];
    for (int k = 0; k < DH; ++k) a = fmaf(grow[k], l2w[k * 10 + t], a);
    lg[t] = a;
  }
  __syncthreads();
  if (t < 10) {
    float m = lg[0];
    for (int i = 1; i < 10; ++i) m = fmaxf(m, lg[i]);
    float sum = 0.f;
    for (int i = 0; i < 10; ++i) sum += expf(lg[i] - m);
    out[g * 10 + t] = lg[t] - m - logf(sum);
  }
}

// ---------------- launch ----------------

extern "C" void kernel_launch(void* const* d_in, const int* in_sizes, int n_in,
                              void* d_out, int out_size, void* d_ws, size_t ws_size,
                              hipStream_t stream) {
  const float* x = (const float*)d_in[0];
  const int* ei = (const int*)d_in[1];
  const int* esrc = ei;
  const int* edst = ei + NE;
  const int* batch = (const int*)d_in[2];
  const float* W[3] = {(const float*)d_in[4], (const float*)d_in[6], (const float*)d_in[8]};
  const float* B[3] = {(const float*)d_in[5], (const float*)d_in[7], (const float*)d_in[9]};
  const float* l1w = (const float*)d_in[10];
  const float* l1b = (const float*)d_in[11];
  const float* l2w = (const float*)d_in[12];
  const float* l2b = (const float*)d_in[13];
  float* out = (float*)d_out;

  char* ws = (char*)d_ws;
  size_t off = 0;
  auto alloc = [&](size_t bytes) {
    char* p = ws + off;
    off = (off + bytes + 255) & ~(size_t)255;
    return p;
  };
  int* offsets = (int*)alloc((size_t)(NN + 1) * 4);
  float* dinv = (float*)alloc((size_t)NN * 4);
  int* csr_src = (int*)alloc((size_t)NE * 4);
  int* start = (int*)alloc((NG + 1) * 4);
  float* pooled = (float*)alloc((size_t)NG * 3 * DH * 4);
  int* tot = (int*)alloc(128 * 4);
  int* bucketBase = (int*)alloc(132 * 4);
  _Float16* Wt = (_Float16*)alloc((size_t)DH * DH * 2);
  unsigned char* hs8 = (unsigned char*)alloc((size_t)NN * DH);  // e5m2 GEMM out (gather buf)
  _Float16* hb = (_Float16*)alloc((size_t)NN * DH * 2);         // aggregate out / next GEMM in

  // CSR-build scratch aliased onto layer buffers (used strictly before the loop)
  int* hist = (int*)hs8;        // 98*391*4 = 153 KB <= 12.8 MB
  int2* pairs = (int2*)hb;      // 12.8 MB <= 25.6 MB

  hipMemsetAsync(pooled, 0, (size_t)NG * 3 * DH * 4, stream);

  k_binhist<<<NBLK_BIN, 256, 0, stream>>>(edst, hist);
  k_bucktot<<<NBUCKU, 256, 0, stream>>>(hist, tot);
  k_buckscan<<<1, 128, 0, stream>>>(tot, bucketBase);
  k_binscan<<<NBUCKU, 256, 0, stream>>>(hist, bucketBase);
  k_binplace<<<NBLK_BIN, 256, 0, stream>>>(esrc, edst, hist, pairs);
  k_place<<<NBUCKU, 256, 0, stream>>>(pairs, bucketBase, offsets, dinv, csr_src);
  k_starts<<<(NN + 255) / 256, 256, 0, stream>>>(batch, start);

  int nGemmBlk = (NN + 127) / 128;
  for (int L = 0; L < 3; ++L) {
    k_transW<<<DH, DH, 0, stream>>>(W[L], Wt);
    if (L == 0)
      k_gemm<true><<<nGemmBlk, 256, 0, stream>>>((const void*)x, Wt, dinv, hs8);
    else
      k_gemm<false><<<nGemmBlk, 256, 0, stream>>>((const void*)hb, Wt, dinv, hs8);
    k_aggregate<<<(NN * 32) / 256, 256, 0, stream>>>(hs8, csr_src, offsets, dinv, B[L],
                                                     batch, hb, pooled, L * DH,
                                                     (L < 2) ? 1 : 0);
  }

  k_head<<<NG, 128, 0, stream>>>(pooled, start, l1w, l1b, l2w, l2b, out);
}

// Round 6
// 417.757 us; speedup vs baseline: 2.4561x; 1.0518x over previous
//
#include <hip/hip_runtime.h>

#define NN 100000
#define NE 1600000
#define DH 128
#define NG 64

// CSR build parameters
#define NBUCKU 98          // ceil(NN/1024) buckets, bucket = dst >> 10
#define EPB 4096           // edges per binning block
#define NBLK_BIN 391       // ceil(NE/EPB)

#define LDH 136            // padded halves per LDS row

typedef __attribute__((ext_vector_type(2))) _Float16 half2v;
typedef __attribute__((ext_vector_type(4))) _Float16 half4;
typedef __attribute__((ext_vector_type(8))) _Float16 half8;
typedef __attribute__((ext_vector_type(4))) float f32x4;

// e5m2 encode: RNE-round fp16 to top byte.
__device__ inline unsigned int enc8(_Float16 h) {
  unsigned short b = __builtin_bit_cast(unsigned short, h);
  unsigned short r = (unsigned short)(b + 0x7F + ((b >> 8) & 1));
  return (unsigned int)(r >> 8);
}
// decode 4 e5m2 bytes -> two half2: {dim0,dim2} and {dim1,dim3} (3 VALU total)
__device__ inline half2v d02(unsigned int u) {
  return __builtin_bit_cast(half2v, (u << 8) & 0xFF00FF00u);
}
__device__ inline half2v d13(unsigned int u) {
  return __builtin_bit_cast(half2v, u & 0xFF00FF00u);
}

// ---------------- CSR build: two-level counting sort ----------------

__global__ __launch_bounds__(256) void k_binhist(const int* __restrict__ dst,
                                                 int* __restrict__ hist) {
  __shared__ int h[NBUCKU];
  if (threadIdx.x < NBUCKU) h[threadIdx.x] = 0;
  __syncthreads();
  int base = blockIdx.x * EPB;
#pragma unroll
  for (int i = 0; i < EPB / 256; ++i) {
    int e = base + i * 256 + threadIdx.x;
    if (e < NE) atomicAdd(&h[dst[e] >> 10], 1);
  }
  __syncthreads();
  if (threadIdx.x < NBUCKU)
    hist[threadIdx.x * NBLK_BIN + blockIdx.x] = h[threadIdx.x];
}

__global__ __launch_bounds__(256) void k_bucktot(const int* __restrict__ hist,
                                                 int* __restrict__ tot) {
  __shared__ int red[256];
  int b = blockIdx.x, t = threadIdx.x;
  int s = 0;
  for (int i = t; i < NBLK_BIN; i += 256) s += hist[b * NBLK_BIN + i];
  red[t] = s;
  __syncthreads();
  for (int off = 128; off > 0; off >>= 1) {
    if (t < off) red[t] += red[t + off];
    __syncthreads();
  }
  if (t == 0) tot[b] = red[0];
}

// Per-bucket exclusive scan across blocks; each block also (redundantly) scans
// the 98 bucket totals in LDS for its seed and writes bucketBase.
__global__ __launch_bounds__(512) void k_binscan(int* __restrict__ hist,
                                                 const int* __restrict__ tot,
                                                 int* __restrict__ bucketBase) {
  __shared__ int bb[NBUCKU];
  __shared__ int v[512];
  int b = blockIdx.x, t = threadIdx.x;
  for (int i = t; i < NBUCKU; i += 512) bb[i] = tot[i];
  int own = (t < NBLK_BIN) ? hist[b * NBLK_BIN + t] : 0;
  v[t] = own;
  __syncthreads();
  if (t == 0) {
    int run = 0;
    for (int i = 0; i < NBUCKU; ++i) { int x = bb[i]; bb[i] = run; run += x; }
    if (b == 0) bucketBase[NBUCKU] = run;
  }
  __syncthreads();
  int seed = bb[b];
  if (t == 0) bucketBase[b] = seed;
  for (int off = 1; off < 512; off <<= 1) {
    int x = (t >= off) ? v[t - off] : 0;
    __syncthreads();
    v[t] += x;
    __syncthreads();
  }
  if (t < NBLK_BIN) hist[b * NBLK_BIN + t] = seed + v[t] - own;  // exclusive + seed
}

// Pass B: place packed (src<<10 | local) into bucket-major regions.
__global__ __launch_bounds__(256) void k_binplace(const int* __restrict__ src,
                                                  const int* __restrict__ dst,
                                                  const int* __restrict__ hist,
                                                  unsigned int* __restrict__ pairs) {
  __shared__ int cur[NBUCKU];
  if (threadIdx.x < NBUCKU)
    cur[threadIdx.x] = hist[threadIdx.x * NBLK_BIN + blockIdx.x];
  __syncthreads();
  int base = blockIdx.x * EPB;
#pragma unroll
  for (int i = 0; i < EPB / 256; ++i) {
    int e = base + i * 256 + threadIdx.x;
    if (e < NE) {
      int d = dst[e];
      int q = atomicAdd(&cur[d >> 10], 1);
      pairs[q] = ((unsigned int)src[e] << 10) | (unsigned int)(d & 1023);
    }
  }
}

__global__ __launch_bounds__(256) void k_place(const unsigned int* __restrict__ pairs,
                                               const int* __restrict__ bucketBase,
                                               int* __restrict__ offsets,
                                               float* __restrict__ dinv,
                                               int* __restrict__ csr_src) {
  __shared__ int cnt[1024];
  __shared__ int tsum[256];
  int b = blockIdx.x, t = threadIdx.x;
  int nodeBase = b << 10;
  for (int i = t; i < 1024; i += 256) cnt[i] = 0;
  __syncthreads();
  int pStart = bucketBase[b], pEnd = bucketBase[b + 1];
  for (int p = pStart + t; p < pEnd; p += 256)
    atomicAdd(&cnt[pairs[p] & 1023], 1);
  __syncthreads();
  int c0 = cnt[t * 4], c1 = cnt[t * 4 + 1], c2 = cnt[t * 4 + 2], c3 = cnt[t * 4 + 3];
  tsum[t] = c0 + c1 + c2 + c3;
  __syncthreads();
  for (int off = 1; off < 256; off <<= 1) {
    int v = (t >= off) ? tsum[t - off] : 0;
    __syncthreads();
    tsum[t] += v;
    __syncthreads();
  }
  int base = pStart + ((t > 0) ? tsum[t - 1] : 0);
  int e0 = base, e1 = base + c0, e2 = e1 + c1, e3 = e2 + c2;
  __syncthreads();
  cnt[t * 4] = e0; cnt[t * 4 + 1] = e1; cnt[t * 4 + 2] = e2; cnt[t * 4 + 3] = e3;
  int g = nodeBase + t * 4;
  if (g < NN)     { offsets[g] = e0;     dinv[g] = rsqrtf((float)c0 + 1.f); }
  if (g + 1 < NN) { offsets[g + 1] = e1; dinv[g + 1] = rsqrtf((float)c1 + 1.f); }
  if (g + 2 < NN) { offsets[g + 2] = e2; dinv[g + 2] = rsqrtf((float)c2 + 1.f); }
  if (g + 3 < NN) { offsets[g + 3] = e3; dinv[g + 3] = rsqrtf((float)c3 + 1.f); }
  if (b == NBUCKU - 1 && t == 0) offsets[NN] = pEnd;
  __syncthreads();
  for (int p = pStart + t; p < pEnd; p += 256) {
    unsigned int pr = pairs[p];
    int pos = atomicAdd(&cnt[pr & 1023], 1);
    csr_src[pos] = (int)(pr >> 10);
  }
}

// ---------------- graph boundaries + pooled zero-init ----------------

__global__ void k_starts(const int* __restrict__ batch, int* __restrict__ start,
                         float* __restrict__ pooled) {
  int i = blockIdx.x * blockDim.x + threadIdx.x;
  if (i < NG * 3 * DH) pooled[i] = 0.f;
  if (i >= NN) return;
  int b = batch[i];
  int prev = (i == 0) ? -1 : batch[i - 1];
  for (int g = prev + 1; g <= b; ++g) start[g] = i;
  if (i == NN - 1) {
    for (int g = b + 1; g <= NG; ++g) start[g] = NN;
  }
}

// ---------------- W transpose to fp16 (all 3 layers) ----------------

__global__ __launch_bounds__(128) void k_transW3(const float* __restrict__ W0,
                                                 const float* __restrict__ W1,
                                                 const float* __restrict__ W2,
                                                 _Float16* __restrict__ Wt) {
  const float* W = (blockIdx.y == 0) ? W0 : (blockIdx.y == 1) ? W1 : W2;
  int n = blockIdx.x;
  int k = threadIdx.x;
  Wt[blockIdx.y * DH * DH + n * DH + k] = (_Float16)W[k * DH + n];
}

// ---------------- MFMA GEMM: Out8 = e5m2( dinv[r] * (A @ W) ) ----------------

template <bool F32IN>
__global__ __launch_bounds__(256) void k_gemm(const void* __restrict__ Ap,
                                              const _Float16* __restrict__ Wt,
                                              const float* __restrict__ dinv,
                                              unsigned char* __restrict__ Out8) {
  __shared__ _Float16 Al[128 * LDH];
  __shared__ _Float16 Wl[128 * LDH];
  int tid = threadIdx.x;
  int rowBase = blockIdx.x * 128;

  if (F32IN) {
    const float* A = (const float*)Ap;
#pragma unroll
    for (int i = 0; i < 16; ++i) {
      int chunk = tid + i * 256;
      int r = chunk >> 5, c = (chunk & 31) * 4;
      int gr = rowBase + r;
      float4 v = {0.f, 0.f, 0.f, 0.f};
      if (gr < NN) v = *(const float4*)(A + (size_t)gr * DH + c);
      half4 h = {(_Float16)v.x, (_Float16)v.y, (_Float16)v.z, (_Float16)v.w};
      *(half4*)&Al[r * LDH + c] = h;
    }
  } else {
    const _Float16* A = (const _Float16*)Ap;
#pragma unroll
    for (int i = 0; i < 8; ++i) {
      int chunk = tid + i * 256;
      int r = chunk >> 4, c = (chunk & 15) * 8;
      int gr = rowBase + r;
      half8 v = {};
      if (gr < NN) v = *(const half8*)(A + (size_t)gr * DH + c);
      *(half8*)&Al[r * LDH + c] = v;
    }
  }
#pragma unroll
  for (int i = 0; i < 8; ++i) {
    int chunk = tid + i * 256;
    int r = chunk >> 4, c = (chunk & 15) * 8;
    *(half8*)&Wl[r * LDH + c] = *(const half8*)(Wt + r * DH + c);
  }
  __syncthreads();

  int wv = tid >> 6;
  int lane = tid & 63;
  int n16 = lane & 15;
  int quad = lane >> 4;

  f32x4 acc[2][8];
#pragma unroll
  for (int mt = 0; mt < 2; ++mt)
#pragma unroll
    for (int ct = 0; ct < 8; ++ct) acc[mt][ct] = (f32x4){0.f, 0.f, 0.f, 0.f};

  const _Float16* a0p = &Al[(wv * 32 + n16) * LDH + quad * 8];
  const _Float16* a1p = a0p + 16 * LDH;
  const _Float16* bp = &Wl[n16 * LDH + quad * 8];

#pragma unroll
  for (int kk = 0; kk < 4; ++kk) {
    half8 af0 = *(const half8*)(a0p + kk * 32);
    half8 af1 = *(const half8*)(a1p + kk * 32);
#pragma unroll
    for (int ct = 0; ct < 8; ++ct) {
      half8 bf = *(const half8*)(bp + (size_t)ct * 16 * LDH + kk * 32);
      acc[0][ct] = __builtin_amdgcn_mfma_f32_16x16x32_f16(af0, bf, acc[0][ct], 0, 0, 0);
      acc[1][ct] = __builtin_amdgcn_mfma_f32_16x16x32_f16(af1, bf, acc[1][ct], 0, 0, 0);
    }
  }

  float dv[2][4];
#pragma unroll
  for (int mt = 0; mt < 2; ++mt)
#pragma unroll
    for (int r = 0; r < 4; ++r) {
      int gr = rowBase + wv * 32 + mt * 16 + quad * 4 + r;
      dv[mt][r] = (gr < NN) ? dinv[gr] : 0.f;
    }
#pragma unroll
  for (int mt = 0; mt < 2; ++mt)
#pragma unroll
    for (int ct = 0; ct < 8; ++ct)
#pragma unroll
      for (int r = 0; r < 4; ++r)
        Al[(wv * 32 + mt * 16 + quad * 4 + r) * LDH + ct * 16 + n16] =
            (_Float16)(acc[mt][ct][r] * dv[mt][r]);
  __syncthreads();

#pragma unroll
  for (int i = 0; i < 8; ++i) {
    int chunk = tid + i * 256;
    int r = chunk >> 4, c = (chunk & 15) * 8;
    int gr = rowBase + r;
    if (gr < NN) {
      half8 v = *(const half8*)&Al[r * LDH + c];
      unsigned int lo = enc8(v[0]) | (enc8(v[1]) << 8) | (enc8(v[2]) << 16) | (enc8(v[3]) << 24);
      unsigned int hi = enc8(v[4]) | (enc8(v[5]) << 8) | (enc8(v[6]) << 16) | (enc8(v[7]) << 24);
      uint2 st = {lo, hi};
      *(uint2*)(Out8 + (size_t)gr * DH + c) = st;
    }
  }
}

// ---------------- aggregation + fused pooling (e5m2 gather, pk_f16 accum) ----

__global__ __launch_bounds__(256) void k_aggregate(const unsigned char* __restrict__ hs8,
                                                   const int* __restrict__ csr_src,
                                                   const int* __restrict__ offsets,
                                                   const float* __restrict__ dinv,
                                                   const float* __restrict__ bias,
                                                   const int* __restrict__ batch,
                                                   _Float16* __restrict__ hout,
                                                   float* __restrict__ pooled,
                                                   int colOff, int writeH) {
  __shared__ float stage[8][DH];
  int tid = threadIdx.x;
  int gid = blockIdx.x * 256 + tid;
  int node = gid >> 5;
  int sub = tid >> 5;
  int lane4 = (gid & 31) * 4;
  int s = offsets[node];
  int e = offsets[node + 1];

  unsigned int us = *(const unsigned int*)(hs8 + (size_t)node * DH + lane4);
  // even/odd accumulator pairs; layout {dim0,dim2} / {dim1,dim3}
  half2v aE0 = d02(us), aE1 = d13(us);
  half2v aO0 = {(_Float16)0, (_Float16)0}, aO1 = {(_Float16)0, (_Float16)0};

  int p = s;
  for (; p + 3 < e; p += 4) {
    int s0 = csr_src[p];
    int s1 = csr_src[p + 1];
    int s2 = csr_src[p + 2];
    int s3 = csr_src[p + 3];
    unsigned int u0 = *(const unsigned int*)(hs8 + (size_t)s0 * DH + lane4);
    unsigned int u1 = *(const unsigned int*)(hs8 + (size_t)s1 * DH + lane4);
    unsigned int u2 = *(const unsigned int*)(hs8 + (size_t)s2 * DH + lane4);
    unsigned int u3 = *(const unsigned int*)(hs8 + (size_t)s3 * DH + lane4);
    aE0 += d02(u0); aE1 += d13(u0);
    aO0 += d02(u1); aO1 += d13(u1);
    aE0 += d02(u2); aE1 += d13(u2);
    aO0 += d02(u3); aO1 += d13(u3);
  }
  for (; p < e; ++p) {
    int s0 = csr_src[p];
    unsigned int u0 = *(const unsigned int*)(hs8 + (size_t)s0 * DH + lane4);
    aE0 += d02(u0); aE1 += d13(u0);
  }

  float ax = (float)aE0[0] + (float)aO0[0];   // dim0
  float ay = (float)aE1[0] + (float)aO1[0];   // dim1
  float az = (float)aE0[1] + (float)aO0[1];   // dim2
  float aw = (float)aE1[1] + (float)aO1[1];   // dim3

  float dv = dinv[node];
  float4 b4 = *(const float4*)(bias + lane4);
  float4 r;
  r.x = fmaxf(fmaf(ax, dv, b4.x), 0.f);
  r.y = fmaxf(fmaf(ay, dv, b4.y), 0.f);
  r.z = fmaxf(fmaf(az, dv, b4.z), 0.f);
  r.w = fmaxf(fmaf(aw, dv, b4.w), 0.f);
  if (writeH) {
    half4 rh = {(_Float16)r.x, (_Float16)r.y, (_Float16)r.z, (_Float16)r.w};
    *(half4*)(hout + (size_t)node * DH + lane4) = rh;
  }

  int nodeFirst = blockIdx.x * 8;
  int gFirst = batch[nodeFirst];
  int gLast = batch[nodeFirst + 7];
  if (gFirst == gLast) {
    *(float4*)&stage[sub][lane4] = r;
    __syncthreads();
    if (tid < DH) {
      float ssum = 0.f;
#pragma unroll
      for (int w = 0; w < 8; ++w) ssum += stage[w][tid];
      atomicAdd(&pooled[gFirst * (3 * DH) + colOff + tid], ssum);
    }
  } else {
    int g = batch[node];
    float* pp = &pooled[g * (3 * DH) + colOff + lane4];
    atomicAdd(pp + 0, r.x);
    atomicAdd(pp + 1, r.y);
    atomicAdd(pp + 2, r.z);
    atomicAdd(pp + 3, r.w);
  }
}

// ---------------- head ----------------

__global__ __launch_bounds__(128) void k_head(const float* __restrict__ pooled,
                                              const int* __restrict__ start,
                                              const float* __restrict__ l1w,
                                              const float* __restrict__ l1b,
                                              const float* __restrict__ l2w,
                                              const float* __restrict__ l2b,
                                              float* __restrict__ out) {
  __shared__ float pr[3 * DH];
  __shared__ float grow[DH];
  __shared__ float lg[16];
  int g = blockIdx.x, t = threadIdx.x;
  float cnt = (float)(start[g + 1] - start[g]);
  float inv = 1.0f / fmaxf(cnt, 1.0f);
  for (int k = t; k < 3 * DH; k += 128) pr[k] = pooled[g * (3 * DH) + k] * inv;
  __syncthreads();
  float acc = l1b[t];
  for (int k = 0; k < 3 * DH; ++k) acc = fmaf(pr[k], l1w[k * DH + t], acc);
  grow[t] = fmaxf(acc, 0.f);
  __syncthreads();
  if (t < 10) {
    float a = l2b[t];
    for (int k = 0; k < DH; ++k) a = fmaf(grow[k], l2w[k * 10 + t], a);
    lg[t] = a;
  }
  __syncthreads();
  if (t < 10) {
    float m = lg[0];
    for (int i = 1; i < 10; ++i) m = fmaxf(m, lg[i]);
    float sum = 0.f;
    for (int i = 0; i < 10; ++i) sum += expf(lg[i] - m);
    out[g * 10 + t] = lg[t] - m - logf(sum);
  }
}

// ---------------- launch ----------------

extern "C" void kernel_launch(void* const* d_in, const int* in_sizes, int n_in,
                              void* d_out, int out_size, void* d_ws, size_t ws_size,
                              hipStream_t stream) {
  const float* x = (const float*)d_in[0];
  const int* ei = (const int*)d_in[1];
  const int* esrc = ei;
  const int* edst = ei + NE;
  const int* batch = (const int*)d_in[2];
  const float* W[3] = {(const float*)d_in[4], (const float*)d_in[6], (const float*)d_in[8]};
  const float* B[3] = {(const float*)d_in[5], (const float*)d_in[7], (const float*)d_in[9]};
  const float* l1w = (const float*)d_in[10];
  const float* l1b = (const float*)d_in[11];
  const float* l2w = (const float*)d_in[12];
  const float* l2b = (const float*)d_in[13];
  float* out = (float*)d_out;

  char* ws = (char*)d_ws;
  size_t off = 0;
  auto alloc = [&](size_t bytes) {
    char* p = ws + off;
    off = (off + bytes + 255) & ~(size_t)255;
    return p;
  };
  int* offsets = (int*)alloc((size_t)(NN + 1) * 4);
  float* dinv = (float*)alloc((size_t)NN * 4);
  int* csr_src = (int*)alloc((size_t)NE * 4);
  int* start = (int*)alloc((NG + 1) * 4);
  float* pooled = (float*)alloc((size_t)NG * 3 * DH * 4);
  int* tot = (int*)alloc(128 * 4);
  int* bucketBase = (int*)alloc(132 * 4);
  _Float16* Wt = (_Float16*)alloc((size_t)3 * DH * DH * 2);
  unsigned char* hs8 = (unsigned char*)alloc((size_t)NN * DH);  // e5m2 GEMM out
  _Float16* hb = (_Float16*)alloc((size_t)NN * DH * 2);         // aggregate out

  // CSR-build scratch aliased onto layer buffers (used strictly before the loop)
  int* hist = (int*)hs8;                 // 98*391*4 = 153 KB <= 12.8 MB
  unsigned int* pairs = (unsigned int*)hb;  // 6.4 MB <= 25.6 MB

  k_binhist<<<NBLK_BIN, 256, 0, stream>>>(edst, hist);
  k_bucktot<<<NBUCKU, 256, 0, stream>>>(hist, tot);
  k_binscan<<<NBUCKU, 512, 0, stream>>>(hist, tot, bucketBase);
  k_binplace<<<NBLK_BIN, 256, 0, stream>>>(esrc, edst, hist, pairs);
  k_place<<<NBUCKU, 256, 0, stream>>>(pairs, bucketBase, offsets, dinv, csr_src);
  k_starts<<<(NN + 255) / 256, 256, 0, stream>>>(batch, start, pooled);
  k_transW3<<<dim3(DH, 3), DH, 0, stream>>>(W[0], W[1], W[2], Wt);

  int nGemmBlk = (NN + 127) / 128;
  for (int L = 0; L < 3; ++L) {
    if (L == 0)
      k_gemm<true><<<nGemmBlk, 256, 0, stream>>>((const void*)x, Wt, dinv, hs8);
    else
      k_gemm<false><<<nGemmBlk, 256, 0, stream>>>((const void*)hb, Wt + (size_t)L * DH * DH,
                                                  dinv, hs8);
    k_aggregate<<<(NN * 32) / 256, 256, 0, stream>>>(hs8, csr_src, offsets, dinv, B[L],
                                                     batch, hb, pooled, L * DH,
                                                     (L < 2) ? 1 : 0);
  }

  k_head<<<NG, 128, 0, stream>>>(pooled, start, l1w, l1b, l2w, l2b, out);
}

// Round 8
// 408.236 us; speedup vs baseline: 2.5134x; 1.0233x over previous
//
#include <hip/hip_runtime.h>

#define NN 100000
#define NE 1600000
#define DH 128
#define NG 64

// CSR build parameters
#define NBUCKU 98          // ceil(NN/1024) buckets, bucket = dst >> 10
#define EPB 4096           // edges per binning block
#define NBLK_BIN 391       // ceil(NE/EPB)

#define LDH 136            // padded halves per LDS row

typedef __attribute__((ext_vector_type(2))) _Float16 half2v;
typedef __attribute__((ext_vector_type(4))) _Float16 half4;
typedef __attribute__((ext_vector_type(8))) _Float16 half8;
typedef __attribute__((ext_vector_type(4))) float f32x4;

// e5m2 encode: RNE-round fp16 to top byte.
__device__ inline unsigned int enc8(_Float16 h) {
  unsigned short b = __builtin_bit_cast(unsigned short, h);
  unsigned short r = (unsigned short)(b + 0x7F + ((b >> 8) & 1));
  return (unsigned int)(r >> 8);
}
// decode 4 e5m2 bytes -> two half2: {dim0,dim2} and {dim1,dim3}
__device__ inline half2v d02(unsigned int u) {
  return __builtin_bit_cast(half2v, (u << 8) & 0xFF00FF00u);
}
__device__ inline half2v d13(unsigned int u) {
  return __builtin_bit_cast(half2v, u & 0xFF00FF00u);
}

// ---------------- binhist + independent preamble work (starts, pooled, transW) ----

__global__ __launch_bounds__(256) void k_binhist(const int* __restrict__ dst,
                                                 int* __restrict__ hist,
                                                 const int* __restrict__ batch,
                                                 int* __restrict__ start,
                                                 float* __restrict__ pooled,
                                                 const float* __restrict__ W0,
                                                 const float* __restrict__ W1,
                                                 const float* __restrict__ W2,
                                                 _Float16* __restrict__ Wt) {
  int gtid = blockIdx.x * 256 + threadIdx.x;
  if (gtid < NG * 3 * DH) pooled[gtid] = 0.f;
  if (gtid < 3 * DH * DH) {
    int l = gtid >> 14;
    int rem = gtid & 16383;
    int n = rem >> 7, k = rem & 127;
    const float* W = (l == 0) ? W0 : (l == 1) ? W1 : W2;
    Wt[(size_t)l * DH * DH + n * DH + k] = (_Float16)W[k * DH + n];
  }
  if (gtid < NN) {
    int bat = batch[gtid];
    int prev = (gtid == 0) ? -1 : batch[gtid - 1];
    for (int g = prev + 1; g <= bat; ++g) start[g] = gtid;
    if (gtid == NN - 1)
      for (int g = bat + 1; g <= NG; ++g) start[g] = NN;
  }

  __shared__ int h[NBUCKU];
  if (threadIdx.x < NBUCKU) h[threadIdx.x] = 0;
  __syncthreads();
  int base = blockIdx.x * EPB;
#pragma unroll
  for (int i = 0; i < EPB / 256; ++i) {
    int e = base + i * 256 + threadIdx.x;
    if (e < NE) atomicAdd(&h[dst[e] >> 10], 1);
  }
  __syncthreads();
  if (threadIdx.x < NBUCKU)
    hist[threadIdx.x * NBLK_BIN + blockIdx.x] = h[threadIdx.x];
}

__global__ __launch_bounds__(256) void k_bucktot(const int* __restrict__ hist,
                                                 int* __restrict__ tot) {
  __shared__ int red[256];
  int b = blockIdx.x, t = threadIdx.x;
  int s = 0;
  for (int i = t; i < NBLK_BIN; i += 256) s += hist[b * NBLK_BIN + i];
  red[t] = s;
  __syncthreads();
  for (int off = 128; off > 0; off >>= 1) {
    if (t < off) red[t] += red[t + off];
    __syncthreads();
  }
  if (t == 0) tot[b] = red[0];
}

// Per-bucket exclusive scan across blocks; each block redundantly scans bucket
// totals in LDS for its seed and writes bucketBase.
__global__ __launch_bounds__(512) void k_binscan(int* __restrict__ hist,
                                                 const int* __restrict__ tot,
                                                 int* __restrict__ bucketBase) {
  __shared__ int bb[NBUCKU];
  __shared__ int v[512];
  int b = blockIdx.x, t = threadIdx.x;
  for (int i = t; i < NBUCKU; i += 512) bb[i] = tot[i];
  int own = (t < NBLK_BIN) ? hist[b * NBLK_BIN + t] : 0;
  v[t] = own;
  __syncthreads();
  if (t == 0) {
    int run = 0;
    for (int i = 0; i < NBUCKU; ++i) { int x = bb[i]; bb[i] = run; run += x; }
    if (b == 0) bucketBase[NBUCKU] = run;
  }
  __syncthreads();
  int seed = bb[b];
  if (t == 0) bucketBase[b] = seed;
  for (int off = 1; off < 512; off <<= 1) {
    int x = (t >= off) ? v[t - off] : 0;
    __syncthreads();
    v[t] += x;
    __syncthreads();
  }
  if (t < NBLK_BIN) hist[b * NBLK_BIN + t] = seed + v[t] - own;  // exclusive + seed
}

__global__ __launch_bounds__(256) void k_binplace(const int* __restrict__ src,
                                                  const int* __restrict__ dst,
                                                  const int* __restrict__ hist,
                                                  unsigned int* __restrict__ pairs) {
  __shared__ int cur[NBUCKU];
  if (threadIdx.x < NBUCKU)
    cur[threadIdx.x] = hist[threadIdx.x * NBLK_BIN + blockIdx.x];
  __syncthreads();
  int base = blockIdx.x * EPB;
#pragma unroll
  for (int i = 0; i < EPB / 256; ++i) {
    int e = base + i * 256 + threadIdx.x;
    if (e < NE) {
      int d = dst[e];
      int q = atomicAdd(&cur[d >> 10], 1);
      pairs[q] = ((unsigned int)src[e] << 10) | (unsigned int)(d & 1023);
    }
  }
}

__global__ __launch_bounds__(256) void k_place(const unsigned int* __restrict__ pairs,
                                               const int* __restrict__ bucketBase,
                                               int* __restrict__ offsets,
                                               float* __restrict__ dinv,
                                               int* __restrict__ csr_src) {
  __shared__ int cnt[1024];
  __shared__ int tsum[256];
  int b = blockIdx.x, t = threadIdx.x;
  int nodeBase = b << 10;
  for (int i = t; i < 1024; i += 256) cnt[i] = 0;
  __syncthreads();
  int pStart = bucketBase[b], pEnd = bucketBase[b + 1];
  for (int p = pStart + t; p < pEnd; p += 256)
    atomicAdd(&cnt[pairs[p] & 1023], 1);
  __syncthreads();
  int c0 = cnt[t * 4], c1 = cnt[t * 4 + 1], c2 = cnt[t * 4 + 2], c3 = cnt[t * 4 + 3];
  tsum[t] = c0 + c1 + c2 + c3;
  __syncthreads();
  for (int off = 1; off < 256; off <<= 1) {
    int v = (t >= off) ? tsum[t - off] : 0;
    __syncthreads();
    tsum[t] += v;
    __syncthreads();
  }
  int base = pStart + ((t > 0) ? tsum[t - 1] : 0);
  int e0 = base, e1 = base + c0, e2 = e1 + c1, e3 = e2 + c2;
  __syncthreads();
  cnt[t * 4] = e0; cnt[t * 4 + 1] = e1; cnt[t * 4 + 2] = e2; cnt[t * 4 + 3] = e3;
  int g = nodeBase + t * 4;
  if (g < NN)     { offsets[g] = e0;     dinv[g] = rsqrtf((float)c0 + 1.f); }
  if (g + 1 < NN) { offsets[g + 1] = e1; dinv[g + 1] = rsqrtf((float)c1 + 1.f); }
  if (g + 2 < NN) { offsets[g + 2] = e2; dinv[g + 2] = rsqrtf((float)c2 + 1.f); }
  if (g + 3 < NN) { offsets[g + 3] = e3; dinv[g + 3] = rsqrtf((float)c3 + 1.f); }
  if (b == NBUCKU - 1 && t == 0) offsets[NN] = pEnd;
  __syncthreads();
  for (int p = pStart + t; p < pEnd; p += 256) {
    unsigned int pr = pairs[p];
    int pos = atomicAdd(&cnt[pr & 1023], 1);
    csr_src[pos] = (int)(pr >> 10);
  }
}

// ---------------- MFMA GEMM: Out8 = e5m2( dinv[r] * (A @ W) ) ----------------
// A-fragments loaded directly from global (no block-level reuse: N=128 = one
// column tile). Only W staged in LDS (34.8 KB -> 4 blocks/CU); W-LDS reused
// as epilogue staging.

template <bool F32IN>
__global__ __launch_bounds__(256) void k_gemm(const void* __restrict__ Ap,
                                              const _Float16* __restrict__ Wt,
                                              const float* __restrict__ dinv,
                                              unsigned char* __restrict__ Out8) {
  __shared__ _Float16 Wl[128 * LDH];
  int tid = threadIdx.x;
  int rowBase = blockIdx.x * 128;

#pragma unroll
  for (int i = 0; i < 8; ++i) {
    int chunk = tid + i * 256;
    int r = chunk >> 4, c = (chunk & 15) * 8;
    *(half8*)&Wl[r * LDH + c] = *(const half8*)(Wt + r * DH + c);
  }

  int wv = tid >> 6;
  int lane = tid & 63;
  int n16 = lane & 15;
  int quad = lane >> 4;

  int r0 = rowBase + wv * 32 + n16;
  int r1 = r0 + 16;

  // A-fragments straight from global
  half8 af[2][4];
  if (F32IN) {
    const float* A = (const float*)Ap;
#pragma unroll
    for (int kk = 0; kk < 4; ++kk) {
      half8 z = {};
      if (r0 < NN) {
        float4 lo = *(const float4*)(A + (size_t)r0 * DH + quad * 8 + kk * 32);
        float4 hi = *(const float4*)(A + (size_t)r0 * DH + quad * 8 + kk * 32 + 4);
        z = (half8){(_Float16)lo.x, (_Float16)lo.y, (_Float16)lo.z, (_Float16)lo.w,
                    (_Float16)hi.x, (_Float16)hi.y, (_Float16)hi.z, (_Float16)hi.w};
      }
      af[0][kk] = z;
      half8 z1 = {};
      if (r1 < NN) {
        float4 lo = *(const float4*)(A + (size_t)r1 * DH + quad * 8 + kk * 32);
        float4 hi = *(const float4*)(A + (size_t)r1 * DH + quad * 8 + kk * 32 + 4);
        z1 = (half8){(_Float16)lo.x, (_Float16)lo.y, (_Float16)lo.z, (_Float16)lo.w,
                     (_Float16)hi.x, (_Float16)hi.y, (_Float16)hi.z, (_Float16)hi.w};
      }
      af[1][kk] = z1;
    }
  } else {
    const _Float16* A = (const _Float16*)Ap;
#pragma unroll
    for (int kk = 0; kk < 4; ++kk) {
      half8 z = {};
      if (r0 < NN) z = *(const half8*)(A + (size_t)r0 * DH + quad * 8 + kk * 32);
      af[0][kk] = z;
      half8 z1 = {};
      if (r1 < NN) z1 = *(const half8*)(A + (size_t)r1 * DH + quad * 8 + kk * 32);
      af[1][kk] = z1;
    }
  }
  __syncthreads();  // Wl ready

  f32x4 acc[2][8];
#pragma unroll
  for (int mt = 0; mt < 2; ++mt)
#pragma unroll
    for (int ct = 0; ct < 8; ++ct) acc[mt][ct] = (f32x4){0.f, 0.f, 0.f, 0.f};

  const _Float16* bp = &Wl[n16 * LDH + quad * 8];
#pragma unroll
  for (int kk = 0; kk < 4; ++kk) {
#pragma unroll
    for (int ct = 0; ct < 8; ++ct) {
      half8 bf = *(const half8*)(bp + (size_t)ct * 16 * LDH + kk * 32);
      acc[0][ct] = __builtin_amdgcn_mfma_f32_16x16x32_f16(af[0][kk], bf, acc[0][ct], 0, 0, 0);
      acc[1][ct] = __builtin_amdgcn_mfma_f32_16x16x32_f16(af[1][kk], bf, acc[1][ct], 0, 0, 0);
    }
  }

  float dv[2][4];
#pragma unroll
  for (int mt = 0; mt < 2; ++mt)
#pragma unroll
    for (int r = 0; r < 4; ++r) {
      int gr = rowBase + wv * 32 + mt * 16 + quad * 4 + r;
      dv[mt][r] = (gr < NN) ? dinv[gr] : 0.f;
    }

  __syncthreads();  // all waves done reading Wl; reuse as epilogue staging
#pragma unroll
  for (int mt = 0; mt < 2; ++mt)
#pragma unroll
    for (int ct = 0; ct < 8; ++ct)
#pragma unroll
      for (int r = 0; r < 4; ++r)
        Wl[(wv * 32 + mt * 16 + quad * 4 + r) * LDH + ct * 16 + n16] =
            (_Float16)(acc[mt][ct][r] * dv[mt][r]);
  __syncthreads();

#pragma unroll
  for (int i = 0; i < 8; ++i) {
    int chunk = tid + i * 256;
    int r = chunk >> 4, c = (chunk & 15) * 8;
    int gr = rowBase + r;
    if (gr < NN) {
      half8 v = *(const half8*)&Wl[r * LDH + c];
      unsigned int lo = enc8(v[0]) | (enc8(v[1]) << 8) | (enc8(v[2]) << 16) | (enc8(v[3]) << 24);
      unsigned int hi = enc8(v[4]) | (enc8(v[5]) << 8) | (enc8(v[6]) << 16) | (enc8(v[7]) << 24);
      uint2 st = {lo, hi};
      *(uint2*)(Out8 + (size_t)gr * DH + c) = st;
    }
  }
}

// ---------------- aggregation + fused pooling (e5m2 gather, pk_f16 accum) ----

__global__ __launch_bounds__(256) void k_aggregate(const unsigned char* __restrict__ hs8,
                                                   const int* __restrict__ csr_src,
                                                   const int* __restrict__ offsets,
                                                   const float* __restrict__ dinv,
                                                   const float* __restrict__ bias,
                                                   const int* __restrict__ batch,
                                                   _Float16* __restrict__ hout,
                                                   float* __restrict__ pooled,
                                                   int colOff, int writeH) {
  __shared__ float stage[8][DH];
  int tid = threadIdx.x;
  int gid = blockIdx.x * 256 + tid;
  int node = gid >> 5;
  int sub = tid >> 5;
  int lane4 = (gid & 31) * 4;
  int s = offsets[node];
  int e = offsets[node + 1];

  unsigned int us = *(const unsigned int*)(hs8 + (size_t)node * DH + lane4);
  half2v aE0 = d02(us), aE1 = d13(us);
  half2v aO0 = {(_Float16)0, (_Float16)0}, aO1 = {(_Float16)0, (_Float16)0};

  int p = s;
  for (; p + 3 < e; p += 4) {
    int s0 = csr_src[p];
    int s1 = csr_src[p + 1];
    int s2 = csr_src[p + 2];
    int s3 = csr_src[p + 3];
    unsigned int u0 = *(const unsigned int*)(hs8 + (size_t)s0 * DH + lane4);
    unsigned int u1 = *(const unsigned int*)(hs8 + (size_t)s1 * DH + lane4);
    unsigned int u2 = *(const unsigned int*)(hs8 + (size_t)s2 * DH + lane4);
    unsigned int u3 = *(const unsigned int*)(hs8 + (size_t)s3 * DH + lane4);
    aE0 += d02(u0); aE1 += d13(u0);
    aO0 += d02(u1); aO1 += d13(u1);
    aE0 += d02(u2); aE1 += d13(u2);
    aO0 += d02(u3); aO1 += d13(u3);
  }
  for (; p < e; ++p) {
    int s0 = csr_src[p];
    unsigned int u0 = *(const unsigned int*)(hs8 + (size_t)s0 * DH + lane4);
    aE0 += d02(u0); aE1 += d13(u0);
  }

  float ax = (float)aE0[0] + (float)aO0[0];
  float ay = (float)aE1[0] + (float)aO1[0];
  float az = (float)aE0[1] + (float)aO0[1];
  float aw = (float)aE1[1] + (float)aO1[1];

  float dv = dinv[node];
  float4 b4 = *(const float4*)(bias + lane4);
  float4 r;
  r.x = fmaxf(fmaf(ax, dv, b4.x), 0.f);
  r.y = fmaxf(fmaf(ay, dv, b4.y), 0.f);
  r.z = fmaxf(fmaf(az, dv, b4.z), 0.f);
  r.w = fmaxf(fmaf(aw, dv, b4.w), 0.f);
  if (writeH) {
    half4 rh = {(_Float16)r.x, (_Float16)r.y, (_Float16)r.z, (_Float16)r.w};
    *(half4*)(hout + (size_t)node * DH + lane4) = rh;
  }

  int nodeFirst = blockIdx.x * 8;
  int gFirst = batch[nodeFirst];
  int gLast = batch[nodeFirst + 7];
  if (gFirst == gLast) {
    *(float4*)&stage[sub][lane4] = r;
    __syncthreads();
    if (tid < DH) {
      float ssum = 0.f;
#pragma unroll
      for (int w = 0; w < 8; ++w) ssum += stage[w][tid];
      atomicAdd(&pooled[gFirst * (3 * DH) + colOff + tid], ssum);
    }
  } else {
    int g = batch[node];
    float* pp = &pooled[g * (3 * DH) + colOff + lane4];
    atomicAdd(pp + 0, r.x);
    atomicAdd(pp + 1, r.y);
    atomicAdd(pp + 2, r.z);
    atomicAdd(pp + 3, r.w);
  }
}

// ---------------- head ----------------

__global__ __launch_bounds__(128) void k_head(const float* __restrict__ pooled,
                                              const int* __restrict__ start,
                                              const float* __restrict__ l1w,
                                              const float* __restrict__ l1b,
                                              const float* __restrict__ l2w,
                                              const float* __restrict__ l2b,
                                              float* __restrict__ out) {
  __shared__ float pr[3 * DH];
  __shared__ float grow[DH];
  __shared__ float lg[16];
  int g = blockIdx.x, t = threadIdx.x;
  float cnt = (float)(start[g + 1] - start[g]);
  float inv = 1.0f / fmaxf(cnt, 1.0f);
  for (int k = t; k < 3 * DH; k += 128) pr[k] = pooled[g * (3 * DH) + k] * inv;
  __syncthreads();
  float acc = l1b[t];
  for (int k = 0; k < 3 * DH; ++k) acc = fmaf(pr[k], l1w[k * DH + t], acc);
  grow[t] = fmaxf(acc, 0.f);
  __syncthreads();
  if (t < 10) {
    float a = l2b[t];
    for (int k = 0; k < DH; ++k) a = fmaf(grow[k], l2w[k * 10 + t], a);
    lg[t] = a;
  }
  __syncthreads();
  if (t < 10) {
    float m = lg[0];
    for (int i = 1; i < 10; ++i) m = fmaxf(m, lg[i]);
    float sum = 0.f;
    for (int i = 0; i < 10; ++i) sum += expf(lg[i] - m);
    out[g * 10 + t] = lg[t] - m - logf(sum);
  }
}

// ---------------- launch ----------------

extern "C" void kernel_launch(void* const* d_in, const int* in_sizes, int n_in,
                              void* d_out, int out_size, void* d_ws, size_t ws_size,
                              hipStream_t stream) {
  const float* x = (const float*)d_in[0];
  const int* ei = (const int*)d_in[1];
  const int* esrc = ei;
  const int* edst = ei + NE;
  const int* batch = (const int*)d_in[2];
  const float* W0 = (const float*)d_in[4];
  const float* W1 = (const float*)d_in[6];
  const float* W2 = (const float*)d_in[8];
  const float* B[3] = {(const float*)d_in[5], (const float*)d_in[7], (const float*)d_in[9]};
  const float* l1w = (const float*)d_in[10];
  const float* l1b = (const float*)d_in[11];
  const float* l2w = (const float*)d_in[12];
  const float* l2b = (const float*)d_in[13];
  float* out = (float*)d_out;

  char* ws = (char*)d_ws;
  size_t off = 0;
  auto alloc = [&](size_t bytes) {
    char* p = ws + off;
    off = (off + bytes + 255) & ~(size_t)255;
    return p;
  };
  int* offsets = (int*)alloc((size_t)(NN + 1) * 4);
  float* dinv = (float*)alloc((size_t)NN * 4);
  int* csr_src = (int*)alloc((size_t)NE * 4);
  int* start = (int*)alloc((NG + 1) * 4);
  float* pooled = (float*)alloc((size_t)NG * 3 * DH * 4);
  int* tot = (int*)alloc(128 * 4);
  int* bucketBase = (int*)alloc(132 * 4);
  _Float16* Wt = (_Float16*)alloc((size_t)3 * DH * DH * 2);
  unsigned char* hs8 = (unsigned char*)alloc((size_t)NN * DH);  // e5m2 GEMM out
  _Float16* hb = (_Float16*)alloc((size_t)NN * DH * 2);         // aggregate out

  // CSR-build scratch aliased onto layer buffers (used strictly before the loop)
  int* hist = (int*)hs8;                   // 98*391*4 = 153 KB <= 12.8 MB
  unsigned int* pairs = (unsigned int*)hb; // 6.4 MB <= 25.6 MB

  k_binhist<<<NBLK_BIN, 256, 0, stream>>>(edst, hist, batch, start, pooled,
                                          W0, W1, W2, Wt);
  k_bucktot<<<NBUCKU, 256, 0, stream>>>(hist, tot);
  k_binscan<<<NBUCKU, 512, 0, stream>>>(hist, tot, bucketBase);
  k_binplace<<<NBLK_BIN, 256, 0, stream>>>(esrc, edst, hist, pairs);
  k_place<<<NBUCKU, 256, 0, stream>>>(pairs, bucketBase, offsets, dinv, csr_src);

  int nGemmBlk = (NN + 127) / 128;
  for (int L = 0; L < 3; ++L) {
    if (L == 0)
      k_gemm<true><<<nGemmBlk, 256, 0, stream>>>((const void*)x, Wt, dinv, hs8);
    else
      k_gemm<false><<<nGemmBlk, 256, 0, stream>>>((const void*)hb, Wt + (size_t)L * DH * DH,
                                                  dinv, hs8);
    k_aggregate<<<(NN * 32) / 256, 256, 0, stream>>>(hs8, csr_src, offsets, dinv, B[L],
                                                     batch, hb, pooled, L * DH,
                                                     (L < 2) ? 1 : 0);
  }

  k_head<<<NG, 128, 0, stream>>>(pooled, start, l1w, l1b, l2w, l2b, out);
}

// Round 9
// 377.339 us; speedup vs baseline: 2.7192x; 1.0819x over previous
//
#include <hip/hip_runtime.h>

#define NN 100000
#define NE 1600000
#define DH 128
#define NG 64

// CSR build parameters
#define NBUCKU 98          // ceil(NN/1024) buckets, bucket = dst >> 10
#define EPB 4096           // edges per binning block
#define NBLK_BIN 391       // ceil(NE/EPB)

#define LDH 136            // padded halves per LDS row

typedef __attribute__((ext_vector_type(2))) _Float16 half2v;
typedef __attribute__((ext_vector_type(4))) _Float16 half4;
typedef __attribute__((ext_vector_type(8))) _Float16 half8;
typedef __attribute__((ext_vector_type(4))) float f32x4;

// e5m2 encode: RNE-round fp16 to top byte.
__device__ inline unsigned int enc8(_Float16 h) {
  unsigned short b = __builtin_bit_cast(unsigned short, h);
  unsigned short r = (unsigned short)(b + 0x7F + ((b >> 8) & 1));
  return (unsigned int)(r >> 8);
}
// decode 4 e5m2 bytes -> two half2: {dim0,dim2} and {dim1,dim3}
__device__ inline half2v d02(unsigned int u) {
  return __builtin_bit_cast(half2v, (u << 8) & 0xFF00FF00u);
}
__device__ inline half2v d13(unsigned int u) {
  return __builtin_bit_cast(half2v, u & 0xFF00FF00u);
}

// ---------------- binhist + independent preamble (starts, pooled, transW) ----

__global__ __launch_bounds__(256) void k_binhist(const int* __restrict__ dst,
                                                 int* __restrict__ hist,
                                                 const int* __restrict__ batch,
                                                 int* __restrict__ startg,
                                                 float* __restrict__ pooled,
                                                 const float* __restrict__ W0,
                                                 const float* __restrict__ W1,
                                                 const float* __restrict__ W2,
                                                 _Float16* __restrict__ Wt) {
  int gtid = blockIdx.x * 256 + threadIdx.x;
  if (gtid < NG * 3 * DH) pooled[gtid] = 0.f;
  if (gtid < 3 * DH * DH) {
    int l = gtid >> 14;
    int rem = gtid & 16383;
    int n = rem >> 7, k = rem & 127;
    const float* W = (l == 0) ? W0 : (l == 1) ? W1 : W2;
    Wt[(size_t)l * DH * DH + n * DH + k] = (_Float16)W[k * DH + n];
  }
  if (gtid < NN) {
    int bat = batch[gtid];
    int prev = (gtid == 0) ? -1 : batch[gtid - 1];
    for (int g = prev + 1; g <= bat; ++g) startg[g] = gtid;
    if (gtid == NN - 1)
      for (int g = bat + 1; g <= NG; ++g) startg[g] = NN;
  }

  __shared__ int h[NBUCKU];
  if (threadIdx.x < NBUCKU) h[threadIdx.x] = 0;
  __syncthreads();
  int base = blockIdx.x * EPB;
#pragma unroll
  for (int i = 0; i < EPB / 256; ++i) {
    int e = base + i * 256 + threadIdx.x;
    if (e < NE) atomicAdd(&h[dst[e] >> 10], 1);
  }
  __syncthreads();
  if (threadIdx.x < NBUCKU)
    hist[threadIdx.x * NBLK_BIN + blockIdx.x] = h[threadIdx.x];
}

// ---------------- fused bucket-total + per-bucket scan ----------------
// Reads hist, writes exclusive+seeded scan to histOut (separate buffer to
// avoid read/write race across blocks).

__global__ __launch_bounds__(512) void k_binscan2(const int* __restrict__ hist,
                                                  int* __restrict__ histOut,
                                                  int* __restrict__ bucketBase) {
  __shared__ int tot[NBUCKU];
  __shared__ int bb[NBUCKU + 1];
  __shared__ int v[512];
  int b = blockIdx.x, t = threadIdx.x;
  if (t < NBUCKU) tot[t] = 0;
  __syncthreads();
  if (t < NBUCKU * 4) {
    int bu = t >> 2, part = t & 3;
    int s = 0;
    for (int i = part; i < NBLK_BIN; i += 4) s += hist[bu * NBLK_BIN + i];
    atomicAdd(&tot[bu], s);
  }
  int own = (t < NBLK_BIN) ? hist[b * NBLK_BIN + t] : 0;
  v[t] = own;
  __syncthreads();
  if (t == 0) {
    int run = 0;
    for (int i = 0; i < NBUCKU; ++i) { bb[i] = run; run += tot[i]; }
    bb[NBUCKU] = run;
    bucketBase[b] = bb[b];
    if (b == 0) bucketBase[NBUCKU] = run;
  }
  __syncthreads();
  int seed = bb[b];
  for (int off = 1; off < 512; off <<= 1) {
    int x = (t >= off) ? v[t - off] : 0;
    __syncthreads();
    v[t] += x;
    __syncthreads();
  }
  if (t < NBLK_BIN) histOut[b * NBLK_BIN + t] = seed + v[t] - own;
}

__global__ __launch_bounds__(256) void k_binplace(const int* __restrict__ src,
                                                  const int* __restrict__ dst,
                                                  const int* __restrict__ histOut,
                                                  unsigned int* __restrict__ pairs) {
  __shared__ int cur[NBUCKU];
  if (threadIdx.x < NBUCKU)
    cur[threadIdx.x] = histOut[threadIdx.x * NBLK_BIN + blockIdx.x];
  __syncthreads();
  int base = blockIdx.x * EPB;
#pragma unroll
  for (int i = 0; i < EPB / 256; ++i) {
    int e = base + i * 256 + threadIdx.x;
    if (e < NE) {
      int d = dst[e];
      int q = atomicAdd(&cur[d >> 10], 1);
      pairs[q] = ((unsigned int)src[e] << 10) | (unsigned int)(d & 1023);
    }
  }
}

__global__ __launch_bounds__(256) void k_place(const unsigned int* __restrict__ pairs,
                                               const int* __restrict__ bucketBase,
                                               int* __restrict__ offsets,
                                               float* __restrict__ dinv,
                                               int* __restrict__ csr_src) {
  __shared__ int cnt[1024];
  __shared__ int tsum[256];
  int b = blockIdx.x, t = threadIdx.x;
  int nodeBase = b << 10;
  for (int i = t; i < 1024; i += 256) cnt[i] = 0;
  __syncthreads();
  int pStart = bucketBase[b], pEnd = bucketBase[b + 1];
  for (int p = pStart + t; p < pEnd; p += 256)
    atomicAdd(&cnt[pairs[p] & 1023], 1);
  __syncthreads();
  int c0 = cnt[t * 4], c1 = cnt[t * 4 + 1], c2 = cnt[t * 4 + 2], c3 = cnt[t * 4 + 3];
  tsum[t] = c0 + c1 + c2 + c3;
  __syncthreads();
  for (int off = 1; off < 256; off <<= 1) {
    int v = (t >= off) ? tsum[t - off] : 0;
    __syncthreads();
    tsum[t] += v;
    __syncthreads();
  }
  int base = pStart + ((t > 0) ? tsum[t - 1] : 0);
  int e0 = base, e1 = base + c0, e2 = e1 + c1, e3 = e2 + c2;
  __syncthreads();
  cnt[t * 4] = e0; cnt[t * 4 + 1] = e1; cnt[t * 4 + 2] = e2; cnt[t * 4 + 3] = e3;
  int g = nodeBase + t * 4;
  if (g < NN)     { offsets[g] = e0;     dinv[g] = rsqrtf((float)c0 + 1.f); }
  if (g + 1 < NN) { offsets[g + 1] = e1; dinv[g + 1] = rsqrtf((float)c1 + 1.f); }
  if (g + 2 < NN) { offsets[g + 2] = e2; dinv[g + 2] = rsqrtf((float)c2 + 1.f); }
  if (g + 3 < NN) { offsets[g + 3] = e3; dinv[g + 3] = rsqrtf((float)c3 + 1.f); }
  if (b == NBUCKU - 1 && t == 0) offsets[NN] = pEnd;
  __syncthreads();
  for (int p = pStart + t; p < pEnd; p += 256) {
    unsigned int pr = pairs[p];
    int pos = atomicAdd(&cnt[pr & 1023], 1);
    csr_src[pos] = (int)(pr >> 10);
  }
}

// ---------------- MFMA GEMM (layer 1 only): Out8 = e5m2(dinv[r]*(x @ W1)) ----

template <bool F32IN>
__global__ __launch_bounds__(256) void k_gemm(const void* __restrict__ Ap,
                                              const _Float16* __restrict__ Wt,
                                              const float* __restrict__ dinv,
                                              unsigned char* __restrict__ Out8) {
  __shared__ _Float16 Wl[128 * LDH];
  int tid = threadIdx.x;
  int rowBase = blockIdx.x * 128;

#pragma unroll
  for (int i = 0; i < 8; ++i) {
    int chunk = tid + i * 256;
    int r = chunk >> 4, c = (chunk & 15) * 8;
    *(half8*)&Wl[r * LDH + c] = *(const half8*)(Wt + r * DH + c);
  }

  int wv = tid >> 6;
  int lane = tid & 63;
  int n16 = lane & 15;
  int quad = lane >> 4;

  int r0 = rowBase + wv * 32 + n16;
  int r1 = r0 + 16;

  half8 af[2][4];
  if (F32IN) {
    const float* A = (const float*)Ap;
#pragma unroll
    for (int kk = 0; kk < 4; ++kk) {
      half8 z = {};
      if (r0 < NN) {
        float4 lo = *(const float4*)(A + (size_t)r0 * DH + quad * 8 + kk * 32);
        float4 hi = *(const float4*)(A + (size_t)r0 * DH + quad * 8 + kk * 32 + 4);
        z = (half8){(_Float16)lo.x, (_Float16)lo.y, (_Float16)lo.z, (_Float16)lo.w,
                    (_Float16)hi.x, (_Float16)hi.y, (_Float16)hi.z, (_Float16)hi.w};
      }
      af[0][kk] = z;
      half8 z1 = {};
      if (r1 < NN) {
        float4 lo = *(const float4*)(A + (size_t)r1 * DH + quad * 8 + kk * 32);
        float4 hi = *(const float4*)(A + (size_t)r1 * DH + quad * 8 + kk * 32 + 4);
        z1 = (half8){(_Float16)lo.x, (_Float16)lo.y, (_Float16)lo.z, (_Float16)lo.w,
                     (_Float16)hi.x, (_Float16)hi.y, (_Float16)hi.z, (_Float16)hi.w};
      }
      af[1][kk] = z1;
    }
  } else {
    const _Float16* A = (const _Float16*)Ap;
#pragma unroll
    for (int kk = 0; kk < 4; ++kk) {
      half8 z = {};
      if (r0 < NN) z = *(const half8*)(A + (size_t)r0 * DH + quad * 8 + kk * 32);
      af[0][kk] = z;
      half8 z1 = {};
      if (r1 < NN) z1 = *(const half8*)(A + (size_t)r1 * DH + quad * 8 + kk * 32);
      af[1][kk] = z1;
    }
  }
  __syncthreads();

  f32x4 acc[2][8];
#pragma unroll
  for (int mt = 0; mt < 2; ++mt)
#pragma unroll
    for (int ct = 0; ct < 8; ++ct) acc[mt][ct] = (f32x4){0.f, 0.f, 0.f, 0.f};

  const _Float16* bp = &Wl[n16 * LDH + quad * 8];
#pragma unroll
  for (int kk = 0; kk < 4; ++kk) {
#pragma unroll
    for (int ct = 0; ct < 8; ++ct) {
      half8 bf = *(const half8*)(bp + (size_t)ct * 16 * LDH + kk * 32);
      acc[0][ct] = __builtin_amdgcn_mfma_f32_16x16x32_f16(af[0][kk], bf, acc[0][ct], 0, 0, 0);
      acc[1][ct] = __builtin_amdgcn_mfma_f32_16x16x32_f16(af[1][kk], bf, acc[1][ct], 0, 0, 0);
    }
  }

  float dv[2][4];
#pragma unroll
  for (int mt = 0; mt < 2; ++mt)
#pragma unroll
    for (int r = 0; r < 4; ++r) {
      int gr = rowBase + wv * 32 + mt * 16 + quad * 4 + r;
      dv[mt][r] = (gr < NN) ? dinv[gr] : 0.f;
    }

  __syncthreads();
#pragma unroll
  for (int mt = 0; mt < 2; ++mt)
#pragma unroll
    for (int ct = 0; ct < 8; ++ct)
#pragma unroll
      for (int r = 0; r < 4; ++r)
        Wl[(wv * 32 + mt * 16 + quad * 4 + r) * LDH + ct * 16 + n16] =
            (_Float16)(acc[mt][ct][r] * dv[mt][r]);
  __syncthreads();

#pragma unroll
  for (int i = 0; i < 8; ++i) {
    int chunk = tid + i * 256;
    int r = chunk >> 4, c = (chunk & 15) * 8;
    int gr = rowBase + r;
    if (gr < NN) {
      half8 v = *(const half8*)&Wl[r * LDH + c];
      unsigned int lo = enc8(v[0]) | (enc8(v[1]) << 8) | (enc8(v[2]) << 16) | (enc8(v[3]) << 24);
      unsigned int hi = enc8(v[4]) | (enc8(v[5]) << 8) | (enc8(v[6]) << 16) | (enc8(v[7]) << 24);
      uint2 st = {lo, hi};
      *(uint2*)(Out8 + (size_t)gr * DH + c) = st;
    }
  }
}

// ---------------- fused aggregate_L + pool_L + GEMM_{L+1} ----------------
// 64 nodes/block, 512 threads. 8 threads/node gather (16 dims = 1 uint4/edge),
// h-tile in LDS fp16 -> pool -> MFMA vs W (LDS) -> e5m2 out messages.

__global__ __launch_bounds__(512) void k_fused(const unsigned char* __restrict__ hs8_in,
                                               const int* __restrict__ csr_src,
                                               const int* __restrict__ offsets,
                                               const float* __restrict__ dinv,
                                               const float* __restrict__ bias,
                                               const int* __restrict__ batch,
                                               const int* __restrict__ startg,
                                               float* __restrict__ pooled,
                                               int colOff,
                                               const _Float16* __restrict__ Wt,
                                               unsigned char* __restrict__ hs8_out) {
  __shared__ _Float16 Hl[64 * LDH];    // 17.4 KB
  __shared__ _Float16 Wl[128 * LDH];   // 34.8 KB
  int tid = threadIdx.x;
  int n0 = blockIdx.x * 64;

  // stage W (2048 chunks of half8)
#pragma unroll
  for (int i = 0; i < 4; ++i) {
    int chunk = tid + i * 512;
    int r = chunk >> 4, c = (chunk & 15) * 8;
    *(half8*)&Wl[r * LDH + c] = *(const half8*)(Wt + r * DH + c);
  }

  // ---- gather phase: 8 threads/node, 16 dims each ----
  int nd = tid >> 3;
  int part = tid & 7;
  int n = n0 + nd;
  bool valid = (n < NN);

  half2v acc[8];
#pragma unroll
  for (int i = 0; i < 8; ++i) acc[i] = (half2v){(_Float16)0, (_Float16)0};

  if (valid) {
    const unsigned char* bp = hs8_in + part * 16;
    uint4 us = *(const uint4*)(bp + (size_t)n * DH);  // self
    acc[0] += d02(us.x); acc[1] += d13(us.x);
    acc[2] += d02(us.y); acc[3] += d13(us.y);
    acc[4] += d02(us.z); acc[5] += d13(us.z);
    acc[6] += d02(us.w); acc[7] += d13(us.w);
    int s = offsets[n], e = offsets[n + 1];
    int p = s;
    for (; p + 3 < e; p += 4) {
      int s0 = csr_src[p], s1 = csr_src[p + 1], s2 = csr_src[p + 2], s3 = csr_src[p + 3];
      uint4 u0 = *(const uint4*)(bp + (size_t)s0 * DH);
      uint4 u1 = *(const uint4*)(bp + (size_t)s1 * DH);
      uint4 u2 = *(const uint4*)(bp + (size_t)s2 * DH);
      uint4 u3 = *(const uint4*)(bp + (size_t)s3 * DH);
      acc[0] += d02(u0.x); acc[1] += d13(u0.x); acc[2] += d02(u0.y); acc[3] += d13(u0.y);
      acc[4] += d02(u0.z); acc[5] += d13(u0.z); acc[6] += d02(u0.w); acc[7] += d13(u0.w);
      acc[0] += d02(u1.x); acc[1] += d13(u1.x); acc[2] += d02(u1.y); acc[3] += d13(u1.y);
      acc[4] += d02(u1.z); acc[5] += d13(u1.z); acc[6] += d02(u1.w); acc[7] += d13(u1.w);
      acc[0] += d02(u2.x); acc[1] += d13(u2.x); acc[2] += d02(u2.y); acc[3] += d13(u2.y);
      acc[4] += d02(u2.z); acc[5] += d13(u2.z); acc[6] += d02(u2.w); acc[7] += d13(u2.w);
      acc[0] += d02(u3.x); acc[1] += d13(u3.x); acc[2] += d02(u3.y); acc[3] += d13(u3.y);
      acc[4] += d02(u3.z); acc[5] += d13(u3.z); acc[6] += d02(u3.w); acc[7] += d13(u3.w);
    }
    for (; p < e; ++p) {
      int s0 = csr_src[p];
      uint4 u0 = *(const uint4*)(bp + (size_t)s0 * DH);
      acc[0] += d02(u0.x); acc[1] += d13(u0.x); acc[2] += d02(u0.y); acc[3] += d13(u0.y);
      acc[4] += d02(u0.z); acc[5] += d13(u0.z); acc[6] += d02(u0.w); acc[7] += d13(u0.w);
    }
  }

  float dv = valid ? dinv[n] : 0.f;
#pragma unroll
  for (int w = 0; w < 4; ++w) {
    int dim = part * 16 + w * 4;
    float4 b4 = *(const float4*)(bias + dim);
    float h0 = valid ? fmaxf(fmaf((float)acc[2 * w][0], dv, b4.x), 0.f) : 0.f;
    float h1 = valid ? fmaxf(fmaf((float)acc[2 * w + 1][0], dv, b4.y), 0.f) : 0.f;
    float h2 = valid ? fmaxf(fmaf((float)acc[2 * w][1], dv, b4.z), 0.f) : 0.f;
    float h3 = valid ? fmaxf(fmaf((float)acc[2 * w + 1][1], dv, b4.w), 0.f) : 0.f;
    half4 hh = {(_Float16)h0, (_Float16)h1, (_Float16)h2, (_Float16)h3};
    *(half4*)&Hl[nd * LDH + dim] = hh;
  }
  __syncthreads();  // Hl + Wl ready

  // ---- pool phase (threads 0..127, one dim each) ----
  if (tid < DH) {
    int nEnd = (n0 + 64 < NN) ? n0 + 64 : NN;
    int gF = batch[n0];
    int gL = batch[nEnd - 1];
    for (int g = gF; g <= gL; ++g) {
      int rs = (startg[g] > n0) ? startg[g] : n0;
      int re = (startg[g + 1] < nEnd) ? startg[g + 1] : nEnd;
      if (re > rs) {
        float sum = 0.f;
        for (int r2 = rs; r2 < re; ++r2) sum += (float)Hl[(r2 - n0) * LDH + tid];
        atomicAdd(&pooled[g * (3 * DH) + colOff + tid], sum);
      }
    }
  }

  // ---- GEMM phase: 8 waves; wave w: m-tile (w>>1), ct half (w&1) ----
  int wv = tid >> 6;
  int lane = tid & 63;
  int n16 = lane & 15;
  int quad = lane >> 4;
  int m16 = wv >> 1;
  int ctB = (wv & 1) * 4;

  f32x4 acc2[4];
#pragma unroll
  for (int ct = 0; ct < 4; ++ct) acc2[ct] = (f32x4){0.f, 0.f, 0.f, 0.f};

  const _Float16* ap = &Hl[(m16 * 16 + n16) * LDH + quad * 8];
#pragma unroll
  for (int kk = 0; kk < 4; ++kk) {
    half8 af = *(const half8*)(ap + kk * 32);
#pragma unroll
    for (int ct = 0; ct < 4; ++ct) {
      half8 bf = *(const half8*)&Wl[((ctB + ct) * 16 + n16) * LDH + quad * 8 + kk * 32];
      acc2[ct] = __builtin_amdgcn_mfma_f32_16x16x32_f16(af, bf, acc2[ct], 0, 0, 0);
    }
  }

  float dvo[4];
#pragma unroll
  for (int rr = 0; rr < 4; ++rr) {
    int gr = n0 + m16 * 16 + quad * 4 + rr;
    dvo[rr] = (gr < NN) ? dinv[gr] : 0.f;
  }

  __syncthreads();  // pool + MFMA reads of Hl done; reuse Hl for epilogue
#pragma unroll
  for (int ct = 0; ct < 4; ++ct)
#pragma unroll
    for (int rr = 0; rr < 4; ++rr)
      Hl[(m16 * 16 + quad * 4 + rr) * LDH + (ctB + ct) * 16 + n16] =
          (_Float16)(acc2[ct][rr] * dvo[rr]);
  __syncthreads();

  // coalesced e5m2 store: 64 rows x 128 B = 1024 chunks of 8 B
#pragma unroll
  for (int i = 0; i < 2; ++i) {
    int chunk = tid + i * 512;
    int r = chunk >> 4, c = (chunk & 15) * 8;
    int gr = n0 + r;
    if (gr < NN) {
      half8 v = *(const half8*)&Hl[r * LDH + c];
      unsigned int lo = enc8(v[0]) | (enc8(v[1]) << 8) | (enc8(v[2]) << 16) | (enc8(v[3]) << 24);
      unsigned int hi = enc8(v[4]) | (enc8(v[5]) << 8) | (enc8(v[6]) << 16) | (enc8(v[7]) << 24);
      uint2 st = {lo, hi};
      *(uint2*)(hs8_out + (size_t)gr * DH + c) = st;
    }
  }
}

// ---------------- final-layer aggregation + pooling (no h output) ----------

__global__ __launch_bounds__(256) void k_aggregate(const unsigned char* __restrict__ hs8,
                                                   const int* __restrict__ csr_src,
                                                   const int* __restrict__ offsets,
                                                   const float* __restrict__ dinv,
                                                   const float* __restrict__ bias,
                                                   const int* __restrict__ batch,
                                                   float* __restrict__ pooled,
                                                   int colOff) {
  __shared__ float stage[8][DH];
  int tid = threadIdx.x;
  int gid = blockIdx.x * 256 + tid;
  int node = gid >> 5;
  int sub = tid >> 5;
  int lane4 = (gid & 31) * 4;
  int s = offsets[node];
  int e = offsets[node + 1];

  unsigned int us = *(const unsigned int*)(hs8 + (size_t)node * DH + lane4);
  half2v aE0 = d02(us), aE1 = d13(us);
  half2v aO0 = {(_Float16)0, (_Float16)0}, aO1 = {(_Float16)0, (_Float16)0};

  int p = s;
  for (; p + 3 < e; p += 4) {
    int s0 = csr_src[p];
    int s1 = csr_src[p + 1];
    int s2 = csr_src[p + 2];
    int s3 = csr_src[p + 3];
    unsigned int u0 = *(const unsigned int*)(hs8 + (size_t)s0 * DH + lane4);
    unsigned int u1 = *(const unsigned int*)(hs8 + (size_t)s1 * DH + lane4);
    unsigned int u2 = *(const unsigned int*)(hs8 + (size_t)s2 * DH + lane4);
    unsigned int u3 = *(const unsigned int*)(hs8 + (size_t)s3 * DH + lane4);
    aE0 += d02(u0); aE1 += d13(u0);
    aO0 += d02(u1); aO1 += d13(u1);
    aE0 += d02(u2); aE1 += d13(u2);
    aO0 += d02(u3); aO1 += d13(u3);
  }
  for (; p < e; ++p) {
    int s0 = csr_src[p];
    unsigned int u0 = *(const unsigned int*)(hs8 + (size_t)s0 * DH + lane4);
    aE0 += d02(u0); aE1 += d13(u0);
  }

  float ax = (float)aE0[0] + (float)aO0[0];
  float ay = (float)aE1[0] + (float)aO1[0];
  float az = (float)aE0[1] + (float)aO0[1];
  float aw = (float)aE1[1] + (float)aO1[1];

  float dv = dinv[node];
  float4 b4 = *(const float4*)(bias + lane4);
  float4 r;
  r.x = fmaxf(fmaf(ax, dv, b4.x), 0.f);
  r.y = fmaxf(fmaf(ay, dv, b4.y), 0.f);
  r.z = fmaxf(fmaf(az, dv, b4.z), 0.f);
  r.w = fmaxf(fmaf(aw, dv, b4.w), 0.f);

  int nodeFirst = blockIdx.x * 8;
  int gFirst = batch[nodeFirst];
  int gLast = batch[nodeFirst + 7];
  if (gFirst == gLast) {
    *(float4*)&stage[sub][lane4] = r;
    __syncthreads();
    if (tid < DH) {
      float ssum = 0.f;
#pragma unroll
      for (int w = 0; w < 8; ++w) ssum += stage[w][tid];
      atomicAdd(&pooled[gFirst * (3 * DH) + colOff + tid], ssum);
    }
  } else {
    int g = batch[node];
    float* pp = &pooled[g * (3 * DH) + colOff + lane4];
    atomicAdd(pp + 0, r.x);
    atomicAdd(pp + 1, r.y);
    atomicAdd(pp + 2, r.z);
    atomicAdd(pp + 3, r.w);
  }
}

// ---------------- head ----------------

__global__ __launch_bounds__(128) void k_head(const float* __restrict__ pooled,
                                              const int* __restrict__ startg,
                                              const float* __restrict__ l1w,
                                              const float* __restrict__ l1b,
                                              const float* __restrict__ l2w,
                                              const float* __restrict__ l2b,
                                              float* __restrict__ out) {
  __shared__ float pr[3 * DH];
  __shared__ float grow[DH];
  __shared__ float lg[16];
  int g = blockIdx.x, t = threadIdx.x;
  float cnt = (float)(startg[g + 1] - startg[g]);
  float inv = 1.0f / fmaxf(cnt, 1.0f);
  for (int k = t; k < 3 * DH; k += 128) pr[k] = pooled[g * (3 * DH) + k] * inv;
  __syncthreads();
  float acc = l1b[t];
  for (int k = 0; k < 3 * DH; ++k) acc = fmaf(pr[k], l1w[k * DH + t], acc);
  grow[t] = fmaxf(acc, 0.f);
  __syncthreads();
  if (t < 10) {
    float a = l2b[t];
    for (int k = 0; k < DH; ++k) a = fmaf(grow[k], l2w[k * 10 + t], a);
    lg[t] = a;
  }
  __syncthreads();
  if (t < 10) {
    float m = lg[0];
    for (int i = 1; i < 10; ++i) m = fmaxf(m, lg[i]);
    float sum = 0.f;
    for (int i = 0; i < 10; ++i) sum += expf(lg[i] - m);
    out[g * 10 + t] = lg[t] - m - logf(sum);
  }
}

// ---------------- launch ----------------

extern "C" void kernel_launch(void* const* d_in, const int* in_sizes, int n_in,
                              void* d_out, int out_size, void* d_ws, size_t ws_size,
                              hipStream_t stream) {
  const float* x = (const float*)d_in[0];
  const int* ei = (const int*)d_in[1];
  const int* esrc = ei;
  const int* edst = ei + NE;
  const int* batch = (const int*)d_in[2];
  const float* W0 = (const float*)d_in[4];
  const float* W1 = (const float*)d_in[6];
  const float* W2 = (const float*)d_in[8];
  const float* B[3] = {(const float*)d_in[5], (const float*)d_in[7], (const float*)d_in[9]};
  const float* l1w = (const float*)d_in[10];
  const float* l1b = (const float*)d_in[11];
  const float* l2w = (const float*)d_in[12];
  const float* l2b = (const float*)d_in[13];
  float* out = (float*)d_out;

  char* ws = (char*)d_ws;
  size_t off = 0;
  auto alloc = [&](size_t bytes) {
    char* p = ws + off;
    off = (off + bytes + 255) & ~(size_t)255;
    return p;
  };
  int* offsets = (int*)alloc((size_t)(NN + 1) * 4);
  float* dinv = (float*)alloc((size_t)NN * 4);
  int* csr_src = (int*)alloc((size_t)NE * 4);
  int* startg = (int*)alloc((NG + 1) * 4);
  float* pooled = (float*)alloc((size_t)NG * 3 * DH * 4);
  int* bucketBase = (int*)alloc(132 * 4);
  _Float16* Wt = (_Float16*)alloc((size_t)3 * DH * DH * 2);
  unsigned char* hs8A = (unsigned char*)alloc((size_t)NN * DH);  // e5m2 messages A
  unsigned char* hs8B = (unsigned char*)alloc((size_t)NN * DH);  // e5m2 messages B
  unsigned int* pairs = (unsigned int*)alloc((size_t)NE * 4);

  // CSR-build scratch aliased onto hs8A (used strictly before gemm0 writes it)
  int* hist = (int*)hs8A;                       // 153 KB
  int* histOut = hist + NBUCKU * NBLK_BIN;      // +153 KB  (<= 12.8 MB)

  k_binhist<<<NBLK_BIN, 256, 0, stream>>>(edst, hist, batch, startg, pooled,
                                          W0, W1, W2, Wt);
  k_binscan2<<<NBUCKU, 512, 0, stream>>>(hist, histOut, bucketBase);
  k_binplace<<<NBLK_BIN, 256, 0, stream>>>(esrc, edst, histOut, pairs);
  k_place<<<NBUCKU, 256, 0, stream>>>(pairs, bucketBase, offsets, dinv, csr_src);

  // layer 1 GEMM: hs8A = e5m2(dinv * (x @ W1))
  k_gemm<true><<<(NN + 127) / 128, 256, 0, stream>>>((const void*)x, Wt, dinv, hs8A);

  int nFusedBlk = (NN + 63) / 64;
  // fused: aggregate L1 -> pool(col 0) -> GEMM W2 -> hs8B
  k_fused<<<nFusedBlk, 512, 0, stream>>>(hs8A, csr_src, offsets, dinv, B[0], batch,
                                         startg, pooled, 0,
                                         Wt + (size_t)1 * DH * DH, hs8B);
  // fused: aggregate L2 -> pool(col DH) -> GEMM W3 -> hs8A
  k_fused<<<nFusedBlk, 512, 0, stream>>>(hs8B, csr_src, offsets, dinv, B[1], batch,
                                         startg, pooled, DH,
                                         Wt + (size_t)2 * DH * DH, hs8A);
  // final aggregate L3 -> pool(col 2*DH)
  k_aggregate<<<(NN * 32) / 256, 256, 0, stream>>>(hs8A, csr_src, offsets, dinv, B[2],
                                                   batch, pooled, 2 * DH);

  k_head<<<NG, 128, 0, stream>>>(pooled, startg, l1w, l1b, l2w, l2b, out);
}